// Round 4
// baseline (1619.893 us; speedup 1.0000x reference)
//
#include <hip/hip_runtime.h>
#include <math.h>

#define NNODES 100000
#define BSHIFT 7
#define BSIZE 128
#define NBUCK ((NNODES + BSIZE - 1) >> BSHIFT)  // 782

// ---------- global bucket histogram (LDS-aggregated) ----------
__global__ __launch_bounds__(256) void k_bhist(const int* __restrict__ dst, int* __restrict__ bcnt, int E) {
    __shared__ int h[NBUCK];
    for (int k = threadIdx.x; k < NBUCK; k += 256) h[k] = 0;
    __syncthreads();
    int nv = E >> 2;
    for (int i = blockIdx.x * 256 + threadIdx.x; i < nv; i += gridDim.x * 256) {
        int4 d = ((const int4*)dst)[i];
        atomicAdd(&h[d.x >> BSHIFT], 1);
        atomicAdd(&h[d.y >> BSHIFT], 1);
        atomicAdd(&h[d.z >> BSHIFT], 1);
        atomicAdd(&h[d.w >> BSHIFT], 1);
    }
    if (blockIdx.x == 0) {
        for (int k = (nv << 2) + threadIdx.x; k < E; k += 256)
            atomicAdd(&h[dst[k] >> BSHIFT], 1);
    }
    __syncthreads();
    for (int k = threadIdx.x; k < NBUCK; k += 256)
        if (h[k]) atomicAdd(&bcnt[k], h[k]);
}

// ---------- scan bucket counts -> bptr (and init bcur) ----------
__global__ __launch_bounds__(1024) void k_bscan(const int* __restrict__ bcnt, int* __restrict__ bptr,
                                                int* __restrict__ bcur, int E) {
    __shared__ int s[1024];
    int t = threadIdx.x;
    int v = (t < NBUCK) ? bcnt[t] : 0;
    s[t] = v;
    __syncthreads();
    #pragma unroll
    for (int off = 1; off < 1024; off <<= 1) {
        int u = (t >= off) ? s[t - off] : 0;
        __syncthreads();
        s[t] += u;
        __syncthreads();
    }
    if (t < NBUCK) {
        int ex = s[t] - v;
        bptr[t] = ex;
        bcur[t] = ex;
    }
    if (t == 0) bptr[NBUCK] = E;
}

// ---------- multisplit scatter with block-level reservation ----------
// staging word = (src << 7) | (dst & 127); src < 2^17 fits.
__global__ __launch_bounds__(256) void k_ms_scatter(const int* __restrict__ src, const int* __restrict__ dst,
                                                    int* __restrict__ bcur, int* __restrict__ staging,
                                                    int E, int chunk) {
    __shared__ int lh[NBUCK];
    __shared__ int lcur[NBUCK];
    int t = threadIdx.x;
    int c0 = blockIdx.x * chunk;
    int c1 = min(E, c0 + chunk);
    for (int k = t; k < NBUCK; k += 256) lh[k] = 0;
    __syncthreads();
    for (int i = c0 + t; i < c1; i += 256)
        atomicAdd(&lh[dst[i] >> BSHIFT], 1);
    __syncthreads();
    // one global atomic per non-empty bucket per block (<= 782 per block)
    for (int k = t; k < NBUCK; k += 256) {
        int c = lh[k];
        lcur[k] = c ? atomicAdd(&bcur[k], c) : 0;
    }
    __syncthreads();
    for (int i = c0 + t; i < c1; i += 256) {
        int d = dst[i];
        int pos = atomicAdd(&lcur[d >> BSHIFT], 1);
        staging[pos] = (src[i] << BSHIFT) | (d & (BSIZE - 1));
    }
}

// ---------- per-node degree -> dinv (one block per bucket) ----------
__global__ __launch_bounds__(256) void k_deg(const int* __restrict__ staging, const int* __restrict__ bptr,
                                             float* __restrict__ dinv, int N) {
    __shared__ int cnt[BSIZE];
    int t = threadIdx.x;
    int b = blockIdx.x;
    if (t < BSIZE) cnt[t] = 0;
    __syncthreads();
    int bbase = bptr[b], bend = bptr[b + 1];
    for (int e = bbase + t; e < bend; e += 256)
        atomicAdd(&cnt[staging[e] & (BSIZE - 1)], 1);
    __syncthreads();
    if (t < BSIZE) {
        int node = (b << BSHIFT) + t;
        if (node < N) dinv[node] = rsqrtf((float)(cnt[t] + 1));  // +1 self-loop
    }
}

// ---------- G = dinv[i] * (X @ W) ----------
__global__ __launch_bounds__(256) void k_transform(const float* __restrict__ X, const float* __restrict__ W,
                                                   const float* __restrict__ dinv, float* __restrict__ G, int N) {
    int lane = threadIdx.x & 63;
    int wid = threadIdx.x >> 6;
    float w[64];
    #pragma unroll
    for (int k = 0; k < 64; k++) w[k] = W[k * 64 + lane];
    int wave = blockIdx.x * 4 + wid;
    int nw = gridDim.x * 4;
    for (int i = wave; i < N; i += nw) {
        const float4* xr = (const float4*)(X + (size_t)i * 64);
        float a0 = 0.f, a1 = 0.f, a2 = 0.f, a3 = 0.f;
        #pragma unroll
        for (int kk = 0; kk < 16; kk++) {
            float4 x4 = xr[kk];
            a0 = fmaf(x4.x, w[4 * kk + 0], a0);
            a1 = fmaf(x4.y, w[4 * kk + 1], a1);
            a2 = fmaf(x4.z, w[4 * kk + 2], a2);
            a3 = fmaf(x4.w, w[4 * kk + 3], a3);
        }
        G[(size_t)i * 64 + lane] = ((a0 + a1) + (a2 + a3)) * dinv[i];
    }
}

// ---------- fused aggregate + epilogue: one block per bucket ----------
// acc[128][64] in LDS; edges gathered full-wave (64 lanes = one G row), 8 in flight per wave.
__global__ __launch_bounds__(256) void k_bucket_agg(const float* __restrict__ G, const int* __restrict__ staging,
                                                    const int* __restrict__ bptr, const float* __restrict__ dinv,
                                                    const float* __restrict__ bias, float* __restrict__ O, int N) {
    __shared__ float acc[BSIZE * 64];  // 32 KB
    int t = threadIdx.x;
    int lane = t & 63;
    int wid = t >> 6;
    float4* a4 = (float4*)acc;
    #pragma unroll
    for (int k = 0; k < 16; k++) a4[t + k * 256] = make_float4(0.f, 0.f, 0.f, 0.f);
    __syncthreads();
    int b = blockIdx.x;
    int bbase = bptr[b], bend = bptr[b + 1];
    int node0 = b << BSHIFT;
    // 8 edges per wave per iteration (independent gathers -> MLP)
    for (int e0 = bbase + wid * 8; e0 < bend; e0 += 32) {
        int pk[8];
        float v[8];
        #pragma unroll
        for (int j = 0; j < 8; j++)
            if (e0 + j < bend) pk[j] = staging[e0 + j];
        #pragma unroll
        for (int j = 0; j < 8; j++)
            if (e0 + j < bend) v[j] = G[(size_t)(pk[j] >> BSHIFT) * 64 + lane];
        #pragma unroll
        for (int j = 0; j < 8; j++)
            if (e0 + j < bend) atomicAdd(&acc[(pk[j] & (BSIZE - 1)) * 64 + lane], v[j]);
    }
    __syncthreads();
    float bl = bias[lane];
    for (int n = wid; n < BSIZE; n += 4) {
        int node = node0 + n;
        if (node >= N) break;
        float self = G[(size_t)node * 64 + lane];
        float r = fmaxf(fmaf(dinv[node], acc[n * 64 + lane] + self, bl), 0.f);
        O[(size_t)node * 64 + lane] = r;
    }
}

// ---------- softmax(H @ Wfc + bfc) ----------
__global__ __launch_bounds__(256) void k_fc_softmax(const float* __restrict__ H, const float* __restrict__ Wfc,
                                                    const float* __restrict__ bfc, float* __restrict__ O, int N) {
    __shared__ float wf[64 * 16];
    __shared__ float bf[16];
    int t = threadIdx.x;
    for (int k = t; k < 1024; k += 256) wf[k] = Wfc[k];
    if (t < 16) bf[t] = bfc[t];
    __syncthreads();
    int gid = blockIdx.x * 256 + t;
    int node = gid >> 4;
    int c = gid & 15;
    if (node >= N) return;
    const float4* hv = (const float4*)(H + (size_t)node * 64);
    float acc = bf[c];
    #pragma unroll
    for (int kk = 0; kk < 16; kk++) {
        float4 h4 = hv[kk];
        acc = fmaf(h4.x, wf[(4 * kk + 0) * 16 + c], acc);
        acc = fmaf(h4.y, wf[(4 * kk + 1) * 16 + c], acc);
        acc = fmaf(h4.z, wf[(4 * kk + 2) * 16 + c], acc);
        acc = fmaf(h4.w, wf[(4 * kk + 3) * 16 + c], acc);
    }
    float m = acc;
    #pragma unroll
    for (int mask = 1; mask < 16; mask <<= 1) m = fmaxf(m, __shfl_xor(m, mask));
    float ex = expf(acc - m);
    float s = ex;
    #pragma unroll
    for (int mask = 1; mask < 16; mask <<= 1) s += __shfl_xor(s, mask);
    O[(size_t)node * 16 + c] = ex / s;
}

extern "C" void kernel_launch(void* const* d_in, const int* in_sizes, int n_in,
                              void* d_out, int out_size, void* d_ws, size_t ws_size,
                              hipStream_t stream) {
    const float* x   = (const float*)d_in[0];
    const int*   ei  = (const int*)d_in[1];
    const float* W1  = (const float*)d_in[2];
    const float* b1  = (const float*)d_in[3];
    const float* W2  = (const float*)d_in[4];
    const float* b2  = (const float*)d_in[5];
    const float* Wfc = (const float*)d_in[6];
    const float* bfc = (const float*)d_in[7];
    float* out = (float*)d_out;
    const int N = NNODES;
    const int E = in_sizes[1] / 2;

    char* ws = (char*)d_ws;
    size_t off = 0;
    auto take = [&](size_t bytes) {
        char* p = ws + off;
        off = (off + bytes + 255) & ~(size_t)255;
        return p;
    };
    float* bufA    = (float*)take((size_t)N * 64 * 4);
    float* bufB    = (float*)take((size_t)N * 64 * 4);
    int*   staging = (int*)take((size_t)E * 4);
    float* dinv    = (float*)take((size_t)N * 4);
    int*   bcnt    = (int*)take((size_t)(NBUCK + 1) * 4);
    int*   bptr    = (int*)take((size_t)(NBUCK + 1) * 4);
    int*   bcur    = (int*)take((size_t)NBUCK * 4);

    const int* e_src = ei;
    const int* e_dst = ei + E;

    hipMemsetAsync(bcnt, 0, (size_t)NBUCK * 4, stream);
    k_bhist<<<256, 256, 0, stream>>>(e_dst, bcnt, E);
    k_bscan<<<1, 1024, 0, stream>>>(bcnt, bptr, bcur, E);
    int chunk = (E + 127) / 128;
    k_ms_scatter<<<128, 256, 0, stream>>>(e_src, e_dst, bcur, staging, E, chunk);
    k_deg<<<NBUCK, 256, 0, stream>>>(staging, bptr, dinv, N);

    k_transform<<<2048, 256, 0, stream>>>(x, W1, dinv, bufA, N);
    k_bucket_agg<<<NBUCK, 256, 0, stream>>>(bufA, staging, bptr, dinv, b1, bufB, N);
    k_transform<<<2048, 256, 0, stream>>>(bufB, W2, dinv, bufA, N);
    k_bucket_agg<<<NBUCK, 256, 0, stream>>>(bufA, staging, bptr, dinv, b2, bufB, N);
    k_fc_softmax<<<(N * 16 + 255) / 256, 256, 0, stream>>>(bufB, Wfc, bfc, out, N);
}

// Round 5
// 386.540 us; speedup vs baseline: 4.1908x; 4.1908x over previous
//
#include <hip/hip_runtime.h>
#include <math.h>

#define NNODES 100000
#define BSHIFT 7
#define BSIZE 128
#define NBUCK ((NNODES + BSIZE - 1) >> BSHIFT)  // 782

// ---------- global bucket histogram (LDS-aggregated) ----------
__global__ __launch_bounds__(256) void k_bhist(const int* __restrict__ dst, int* __restrict__ bcnt, int E) {
    __shared__ int h[NBUCK];
    for (int k = threadIdx.x; k < NBUCK; k += 256) h[k] = 0;
    __syncthreads();
    int nv = E >> 2;
    for (int i = blockIdx.x * 256 + threadIdx.x; i < nv; i += gridDim.x * 256) {
        int4 d = ((const int4*)dst)[i];
        atomicAdd(&h[d.x >> BSHIFT], 1);
        atomicAdd(&h[d.y >> BSHIFT], 1);
        atomicAdd(&h[d.z >> BSHIFT], 1);
        atomicAdd(&h[d.w >> BSHIFT], 1);
    }
    if (blockIdx.x == 0) {
        for (int k = (nv << 2) + threadIdx.x; k < E; k += 256)
            atomicAdd(&h[dst[k] >> BSHIFT], 1);
    }
    __syncthreads();
    for (int k = threadIdx.x; k < NBUCK; k += 256)
        if (h[k]) atomicAdd(&bcnt[k], h[k]);
}

// ---------- scan bucket counts -> bptr/bcur; rowptr[N]=E ----------
__global__ __launch_bounds__(1024) void k_bscan(const int* __restrict__ bcnt, int* __restrict__ bptr,
                                                int* __restrict__ bcur, int* __restrict__ rowptr,
                                                int N, int E) {
    __shared__ int s[1024];
    int t = threadIdx.x;
    int v = (t < NBUCK) ? bcnt[t] : 0;
    s[t] = v;
    __syncthreads();
    #pragma unroll
    for (int off = 1; off < 1024; off <<= 1) {
        int u = (t >= off) ? s[t - off] : 0;
        __syncthreads();
        s[t] += u;
        __syncthreads();
    }
    if (t < NBUCK) {
        int ex = s[t] - v;
        bptr[t] = ex;
        bcur[t] = ex;
    }
    if (t == 0) {
        bptr[NBUCK] = E;
        rowptr[N] = E;
    }
}

// ---------- multisplit scatter with block-level reservation ----------
// staging word = (src << 7) | (dst & 127); src < 2^17 fits.
__global__ __launch_bounds__(256) void k_ms_scatter(const int* __restrict__ src, const int* __restrict__ dst,
                                                    int* __restrict__ bcur, int* __restrict__ staging,
                                                    int E, int chunk) {
    __shared__ int lh[NBUCK];
    __shared__ int lcur[NBUCK];
    int t = threadIdx.x;
    int c0 = blockIdx.x * chunk;
    int c1 = min(E, c0 + chunk);
    for (int k = t; k < NBUCK; k += 256) lh[k] = 0;
    __syncthreads();
    for (int i = c0 + t; i < c1; i += 256)
        atomicAdd(&lh[dst[i] >> BSHIFT], 1);
    __syncthreads();
    for (int k = t; k < NBUCK; k += 256) {
        int c = lh[k];
        lcur[k] = c ? atomicAdd(&bcur[k], c) : 0;
    }
    __syncthreads();
    for (int i = c0 + t; i < c1; i += 256) {
        int d = dst[i];
        int pos = atomicAdd(&lcur[d >> BSHIFT], 1);
        staging[pos] = (src[i] << BSHIFT) | (d & (BSIZE - 1));
    }
}

// ---------- per-bucket CSR: rowptr + dinv + bucket-local ssort ----------
__global__ __launch_bounds__(256) void k_bucket_csr(const int* __restrict__ staging, const int* __restrict__ bptr,
                                                    int* __restrict__ rowptr, int* __restrict__ ssort,
                                                    float* __restrict__ dinv, int N) {
    __shared__ int lcnt[BSIZE], lpre[BSIZE];
    int b = blockIdx.x, t = threadIdx.x;
    int node0 = b << BSHIFT;
    int bbase = bptr[b], bend = bptr[b + 1];
    if (t < BSIZE) lcnt[t] = 0;
    __syncthreads();
    for (int e = bbase + t; e < bend; e += 256)
        atomicAdd(&lcnt[staging[e] & (BSIZE - 1)], 1);
    __syncthreads();
    if (t < BSIZE) lpre[t] = lcnt[t];
    __syncthreads();
    #pragma unroll
    for (int off = 1; off < BSIZE; off <<= 1) {
        int u = 0;
        if (t < BSIZE && t >= off) u = lpre[t - off];
        __syncthreads();
        if (t < BSIZE) lpre[t] += u;
        __syncthreads();
    }
    if (t < BSIZE) {
        int node = node0 + t;
        if (node < N) {
            rowptr[node] = bbase + lpre[t] - lcnt[t];
            dinv[node] = rsqrtf((float)(lcnt[t] + 1));  // +1 self-loop
        }
        lpre[t] -= lcnt[t];  // exclusive prefix -> local cursor
    }
    __syncthreads();
    for (int e = bbase + t; e < bend; e += 256) {
        int p = staging[e];
        int pos = atomicAdd(&lpre[p & (BSIZE - 1)], 1);
        ssort[bbase + pos] = p >> BSHIFT;  // writes stay in this bucket's segment
    }
}

// ---------- G = dinv[i] * (X @ W) ----------
__global__ __launch_bounds__(256) void k_transform(const float* __restrict__ X, const float* __restrict__ W,
                                                   const float* __restrict__ dinv, float* __restrict__ G, int N) {
    int lane = threadIdx.x & 63;
    int wid = threadIdx.x >> 6;
    float w[64];
    #pragma unroll
    for (int k = 0; k < 64; k++) w[k] = W[k * 64 + lane];
    int wave = blockIdx.x * 4 + wid;
    int nw = gridDim.x * 4;
    for (int i = wave; i < N; i += nw) {
        const float4* xr = (const float4*)(X + (size_t)i * 64);
        float a0 = 0.f, a1 = 0.f, a2 = 0.f, a3 = 0.f;
        #pragma unroll
        for (int kk = 0; kk < 16; kk++) {
            float4 x4 = xr[kk];
            a0 = fmaf(x4.x, w[4 * kk + 0], a0);
            a1 = fmaf(x4.y, w[4 * kk + 1], a1);
            a2 = fmaf(x4.z, w[4 * kk + 2], a2);
            a3 = fmaf(x4.w, w[4 * kk + 3], a3);
        }
        G[(size_t)i * 64 + lane] = ((a0 + a1) + (a2 + a3)) * dinv[i];
    }
}

// ---------- out = relu(dinv[i] * (G[i] + sum_j G[j]) + b) ----------
// wave per node; lane = 16*sub + l; 16 edges in flight (4 per sub).
__global__ __launch_bounds__(256) void k_agg(const float* __restrict__ G, const int* __restrict__ rowptr,
                                             const int* __restrict__ ssort, const float* __restrict__ dinv,
                                             const float* __restrict__ bias, float* __restrict__ O, int N) {
    int lane = threadIdx.x & 63;
    int wid = threadIdx.x >> 6;
    int sub = lane >> 4;
    int l = lane & 15;
    int i = blockIdx.x * 4 + wid;
    if (i >= N) return;
    int beg = rowptr[i], end = rowptr[i + 1];
    float ax = 0.f, ay = 0.f, az = 0.f, aw = 0.f;
    int e = beg + sub;
    for (; e + 12 < end; e += 16) {
        int s0 = ssort[e];
        int s1 = ssort[e + 4];
        int s2 = ssort[e + 8];
        int s3 = ssort[e + 12];
        float4 g0 = *(const float4*)(G + (size_t)s0 * 64 + 4 * l);
        float4 g1 = *(const float4*)(G + (size_t)s1 * 64 + 4 * l);
        float4 g2 = *(const float4*)(G + (size_t)s2 * 64 + 4 * l);
        float4 g3 = *(const float4*)(G + (size_t)s3 * 64 + 4 * l);
        ax += (g0.x + g1.x) + (g2.x + g3.x);
        ay += (g0.y + g1.y) + (g2.y + g3.y);
        az += (g0.z + g1.z) + (g2.z + g3.z);
        aw += (g0.w + g1.w) + (g2.w + g3.w);
    }
    for (; e < end; e += 4) {
        int s0 = ssort[e];
        float4 g0 = *(const float4*)(G + (size_t)s0 * 64 + 4 * l);
        ax += g0.x; ay += g0.y; az += g0.z; aw += g0.w;
    }
    #pragma unroll
    for (int mask = 16; mask <= 32; mask <<= 1) {
        ax += __shfl_xor(ax, mask);
        ay += __shfl_xor(ay, mask);
        az += __shfl_xor(az, mask);
        aw += __shfl_xor(aw, mask);
    }
    float4 gs = *(const float4*)(G + (size_t)i * 64 + 4 * l);
    float4 b4 = *(const float4*)(bias + 4 * l);
    float di = dinv[i];
    if (sub == 0) {
        float4 r;
        r.x = fmaxf(fmaf(di, ax + gs.x, b4.x), 0.f);
        r.y = fmaxf(fmaf(di, ay + gs.y, b4.y), 0.f);
        r.z = fmaxf(fmaf(di, az + gs.z, b4.z), 0.f);
        r.w = fmaxf(fmaf(di, aw + gs.w, b4.w), 0.f);
        *(float4*)(O + (size_t)i * 64 + 4 * l) = r;
    }
}

// ---------- softmax(H @ Wfc + bfc) ----------
__global__ __launch_bounds__(256) void k_fc_softmax(const float* __restrict__ H, const float* __restrict__ Wfc,
                                                    const float* __restrict__ bfc, float* __restrict__ O, int N) {
    __shared__ float wf[64 * 16];
    __shared__ float bf[16];
    int t = threadIdx.x;
    for (int k = t; k < 1024; k += 256) wf[k] = Wfc[k];
    if (t < 16) bf[t] = bfc[t];
    __syncthreads();
    int gid = blockIdx.x * 256 + t;
    int node = gid >> 4;
    int c = gid & 15;
    if (node >= N) return;
    const float4* hv = (const float4*)(H + (size_t)node * 64);
    float acc = bf[c];
    #pragma unroll
    for (int kk = 0; kk < 16; kk++) {
        float4 h4 = hv[kk];
        acc = fmaf(h4.x, wf[(4 * kk + 0) * 16 + c], acc);
        acc = fmaf(h4.y, wf[(4 * kk + 1) * 16 + c], acc);
        acc = fmaf(h4.z, wf[(4 * kk + 2) * 16 + c], acc);
        acc = fmaf(h4.w, wf[(4 * kk + 3) * 16 + c], acc);
    }
    float m = acc;
    #pragma unroll
    for (int mask = 1; mask < 16; mask <<= 1) m = fmaxf(m, __shfl_xor(m, mask));
    float ex = expf(acc - m);
    float s = ex;
    #pragma unroll
    for (int mask = 1; mask < 16; mask <<= 1) s += __shfl_xor(s, mask);
    O[(size_t)node * 16 + c] = ex / s;
}

extern "C" void kernel_launch(void* const* d_in, const int* in_sizes, int n_in,
                              void* d_out, int out_size, void* d_ws, size_t ws_size,
                              hipStream_t stream) {
    const float* x   = (const float*)d_in[0];
    const int*   ei  = (const int*)d_in[1];
    const float* W1  = (const float*)d_in[2];
    const float* b1  = (const float*)d_in[3];
    const float* W2  = (const float*)d_in[4];
    const float* b2  = (const float*)d_in[5];
    const float* Wfc = (const float*)d_in[6];
    const float* bfc = (const float*)d_in[7];
    float* out = (float*)d_out;
    const int N = NNODES;
    const int E = in_sizes[1] / 2;

    char* ws = (char*)d_ws;
    size_t off = 0;
    auto take = [&](size_t bytes) {
        char* p = ws + off;
        off = (off + bytes + 255) & ~(size_t)255;
        return p;
    };
    float* bufA    = (float*)take((size_t)N * 64 * 4);  // staging aliases bufA
    float* bufB    = (float*)take((size_t)N * 64 * 4);
    int*   ssort   = (int*)take((size_t)E * 4);
    int*   rowptr  = (int*)take((size_t)(N + 1) * 4);
    float* dinv    = (float*)take((size_t)N * 4);
    int*   bcnt    = (int*)take((size_t)(NBUCK + 1) * 4);
    int*   bptr    = (int*)take((size_t)(NBUCK + 1) * 4);
    int*   bcur    = (int*)take((size_t)NBUCK * 4);
    int*   staging = (int*)bufA;  // consumed by k_bucket_csr before transform writes bufA

    const int* e_src = ei;
    const int* e_dst = ei + E;

    hipMemsetAsync(bcnt, 0, (size_t)NBUCK * 4, stream);
    k_bhist<<<256, 256, 0, stream>>>(e_dst, bcnt, E);
    k_bscan<<<1, 1024, 0, stream>>>(bcnt, bptr, bcur, rowptr, N, E);
    int chunk = (E + 127) / 128;
    k_ms_scatter<<<128, 256, 0, stream>>>(e_src, e_dst, bcur, staging, E, chunk);
    k_bucket_csr<<<NBUCK, 256, 0, stream>>>(staging, bptr, rowptr, ssort, dinv, N);

    k_transform<<<2048, 256, 0, stream>>>(x, W1, dinv, bufA, N);
    k_agg<<<(N + 3) / 4, 256, 0, stream>>>(bufA, rowptr, ssort, dinv, b1, bufB, N);
    k_transform<<<2048, 256, 0, stream>>>(bufB, W2, dinv, bufA, N);
    k_agg<<<(N + 3) / 4, 256, 0, stream>>>(bufA, rowptr, ssort, dinv, b2, bufB, N);
    k_fc_softmax<<<(N * 16 + 255) / 256, 256, 0, stream>>>(bufB, Wfc, bfc, out, N);
}

// Round 7
// 302.192 us; speedup vs baseline: 5.3605x; 1.2791x over previous
//
#include <hip/hip_runtime.h>
#include <math.h>

#define NNODES 100000
#define BSHIFT 7
#define BSIZE 128
#define NBUCK ((NNODES + BSIZE - 1) >> BSHIFT)  // 782

// ---------- global bucket histogram (LDS-aggregated) ----------
__global__ __launch_bounds__(256) void k_bhist(const int* __restrict__ dst, int* __restrict__ bcnt, int E) {
    __shared__ int h[NBUCK];
    for (int k = threadIdx.x; k < NBUCK; k += 256) h[k] = 0;
    __syncthreads();
    int nv = E >> 2;
    for (int i = blockIdx.x * 256 + threadIdx.x; i < nv; i += gridDim.x * 256) {
        int4 d = ((const int4*)dst)[i];
        atomicAdd(&h[d.x >> BSHIFT], 1);
        atomicAdd(&h[d.y >> BSHIFT], 1);
        atomicAdd(&h[d.z >> BSHIFT], 1);
        atomicAdd(&h[d.w >> BSHIFT], 1);
    }
    if (blockIdx.x == 0) {
        for (int k = (nv << 2) + threadIdx.x; k < E; k += 256)
            atomicAdd(&h[dst[k] >> BSHIFT], 1);
    }
    __syncthreads();
    for (int k = threadIdx.x; k < NBUCK; k += 256)
        if (h[k]) atomicAdd(&bcnt[k], h[k]);
}

// ---------- scan bucket counts -> bptr/bcur; rowptr[N]=E ----------
__global__ __launch_bounds__(1024) void k_bscan(const int* __restrict__ bcnt, int* __restrict__ bptr,
                                                int* __restrict__ bcur, int* __restrict__ rowptr,
                                                int N, int E) {
    __shared__ int s[1024];
    int t = threadIdx.x;
    int v = (t < NBUCK) ? bcnt[t] : 0;
    s[t] = v;
    __syncthreads();
    #pragma unroll
    for (int off = 1; off < 1024; off <<= 1) {
        int u = (t >= off) ? s[t - off] : 0;
        __syncthreads();
        s[t] += u;
        __syncthreads();
    }
    if (t < NBUCK) {
        int ex = s[t] - v;
        bptr[t] = ex;
        bcur[t] = ex;
    }
    if (t == 0) {
        bptr[NBUCK] = E;
        rowptr[N] = E;
    }
}

// ---------- multisplit scatter with block-level reservation ----------
// staging word = (src << 7) | (dst & 127); src < 2^17 fits.
__global__ __launch_bounds__(256) void k_ms_scatter(const int* __restrict__ src, const int* __restrict__ dst,
                                                    int* __restrict__ bcur, int* __restrict__ staging,
                                                    int E, int chunk) {
    __shared__ int lh[NBUCK];
    __shared__ int lcur[NBUCK];
    int t = threadIdx.x;
    int c0 = blockIdx.x * chunk;
    int c1 = min(E, c0 + chunk);
    for (int k = t; k < NBUCK; k += 256) lh[k] = 0;
    __syncthreads();
    for (int i = c0 + t; i < c1; i += 256)
        atomicAdd(&lh[dst[i] >> BSHIFT], 1);
    __syncthreads();
    for (int k = t; k < NBUCK; k += 256) {
        int c = lh[k];
        lcur[k] = c ? atomicAdd(&bcur[k], c) : 0;
    }
    __syncthreads();
    for (int i = c0 + t; i < c1; i += 256) {
        int d = dst[i];
        int pos = atomicAdd(&lcur[d >> BSHIFT], 1);
        staging[pos] = (src[i] << BSHIFT) | (d & (BSIZE - 1));
    }
}

// ---------- per-bucket CSR: rowptr + dinv + bucket-local ssort ----------
__global__ __launch_bounds__(256) void k_bucket_csr(const int* __restrict__ staging, const int* __restrict__ bptr,
                                                    int* __restrict__ rowptr, int* __restrict__ ssort,
                                                    float* __restrict__ dinv, int N) {
    __shared__ int lcnt[BSIZE], lpre[BSIZE];
    int b = blockIdx.x, t = threadIdx.x;
    int node0 = b << BSHIFT;
    int bbase = bptr[b], bend = bptr[b + 1];
    if (t < BSIZE) lcnt[t] = 0;
    __syncthreads();
    for (int e = bbase + t; e < bend; e += 256)
        atomicAdd(&lcnt[staging[e] & (BSIZE - 1)], 1);
    __syncthreads();
    if (t < BSIZE) lpre[t] = lcnt[t];
    __syncthreads();
    #pragma unroll
    for (int off = 1; off < BSIZE; off <<= 1) {
        int u = 0;
        if (t < BSIZE && t >= off) u = lpre[t - off];
        __syncthreads();
        if (t < BSIZE) lpre[t] += u;
        __syncthreads();
    }
    if (t < BSIZE) {
        int node = node0 + t;
        if (node < N) {
            rowptr[node] = bbase + lpre[t] - lcnt[t];
            dinv[node] = rsqrtf((float)(lcnt[t] + 1));  // +1 self-loop
        }
        lpre[t] -= lcnt[t];  // exclusive prefix -> local cursor
    }
    __syncthreads();
    for (int e = bbase + t; e < bend; e += 256) {
        int p = staging[e];
        int pos = atomicAdd(&lpre[p & (BSIZE - 1)], 1);
        ssort[bbase + pos] = p >> BSHIFT;  // writes stay in this bucket's segment
    }
}

// ---------- G = dinv[i] * (X @ W), LDS-tiled, thread-per-node ----------
// block = 128 threads; Xs[128][65] (padded, conflict-free), Ws[64][64] broadcast reads.
__global__ __launch_bounds__(128) void k_transform2(const float* __restrict__ X, const float* __restrict__ W,
                                                    const float* __restrict__ dinv, float* __restrict__ G, int N) {
    __shared__ float Xs[128 * 65];
    __shared__ float Ws[64 * 64];
    int t = threadIdx.x;
    int node0 = blockIdx.x << 7;
    // stage W: 4096 floats = 1024 float4 = 8 per thread
    {
        const float4* W4 = (const float4*)W;
        float4* Ws4 = (float4*)Ws;
        #pragma unroll
        for (int j = 0; j < 8; j++) Ws4[j * 128 + t] = W4[j * 128 + t];
    }
    // stage X tile (2048 float4), coalesced; pad rows to 65 floats
    {
        const float4* X4 = (const float4*)X;
        int lim4 = N << 4;
        #pragma unroll
        for (int ii = 0; ii < 16; ii++) {
            int f = ii * 128 + t;
            int row = f >> 4, cq = f & 15;
            int gi = (node0 << 4) + f;
            float4 v = make_float4(0.f, 0.f, 0.f, 0.f);
            if (gi < lim4) v = X4[gi];
            *(float4*)&Xs[row * 65 + cq * 4] = v;
        }
    }
    __syncthreads();
    float acc[64];
    #pragma unroll
    for (int c = 0; c < 64; c++) acc[c] = 0.f;
    int xbase = t * 65;
    for (int k = 0; k < 64; k++) {
        float xk = Xs[xbase + k];           // 2-way bank alias = free
        const float4* wr = (const float4*)&Ws[k * 64];
        #pragma unroll
        for (int cb = 0; cb < 16; cb++) {
            float4 w4 = wr[cb];             // uniform -> broadcast
            acc[cb * 4 + 0] = fmaf(xk, w4.x, acc[cb * 4 + 0]);
            acc[cb * 4 + 1] = fmaf(xk, w4.y, acc[cb * 4 + 1]);
            acc[cb * 4 + 2] = fmaf(xk, w4.z, acc[cb * 4 + 2]);
            acc[cb * 4 + 3] = fmaf(xk, w4.w, acc[cb * 4 + 3]);
        }
    }
    int node = node0 + t;
    if (node < N) {
        float di = dinv[node];
        float4* g4 = (float4*)(G + (size_t)node * 64);
        #pragma unroll
        for (int cb = 0; cb < 16; cb++) {
            float4 r;
            r.x = acc[cb * 4 + 0] * di;
            r.y = acc[cb * 4 + 1] * di;
            r.z = acc[cb * 4 + 2] * di;
            r.w = acc[cb * 4 + 3] * di;
            g4[cb] = r;
        }
    }
}

// ---------- out = relu(dinv[i] * (G[i] + sum_j G[j]) + b) ----------
// wave per node; lane = 16*sub + l; 16 edges in flight (4 per sub).
__global__ __launch_bounds__(256) void k_agg(const float* __restrict__ G, const int* __restrict__ rowptr,
                                             const int* __restrict__ ssort, const float* __restrict__ dinv,
                                             const float* __restrict__ bias, float* __restrict__ O, int N) {
    int lane = threadIdx.x & 63;
    int wid = threadIdx.x >> 6;
    int sub = lane >> 4;
    int l = lane & 15;
    int i = blockIdx.x * 4 + wid;
    if (i >= N) return;
    int beg = rowptr[i], end = rowptr[i + 1];
    float ax = 0.f, ay = 0.f, az = 0.f, aw = 0.f;
    int e = beg + sub;
    for (; e + 12 < end; e += 16) {
        int s0 = ssort[e];
        int s1 = ssort[e + 4];
        int s2 = ssort[e + 8];
        int s3 = ssort[e + 12];
        float4 g0 = *(const float4*)(G + (size_t)s0 * 64 + 4 * l);
        float4 g1 = *(const float4*)(G + (size_t)s1 * 64 + 4 * l);
        float4 g2 = *(const float4*)(G + (size_t)s2 * 64 + 4 * l);
        float4 g3 = *(const float4*)(G + (size_t)s3 * 64 + 4 * l);
        ax += (g0.x + g1.x) + (g2.x + g3.x);
        ay += (g0.y + g1.y) + (g2.y + g3.y);
        az += (g0.z + g1.z) + (g2.z + g3.z);
        aw += (g0.w + g1.w) + (g2.w + g3.w);
    }
    for (; e < end; e += 4) {
        int s0 = ssort[e];
        float4 g0 = *(const float4*)(G + (size_t)s0 * 64 + 4 * l);
        ax += g0.x; ay += g0.y; az += g0.z; aw += g0.w;
    }
    #pragma unroll
    for (int mask = 16; mask <= 32; mask <<= 1) {
        ax += __shfl_xor(ax, mask);
        ay += __shfl_xor(ay, mask);
        az += __shfl_xor(az, mask);
        aw += __shfl_xor(aw, mask);
    }
    float4 gs = *(const float4*)(G + (size_t)i * 64 + 4 * l);
    float4 b4 = *(const float4*)(bias + 4 * l);
    float di = dinv[i];
    if (sub == 0) {
        float4 r;
        r.x = fmaxf(fmaf(di, ax + gs.x, b4.x), 0.f);
        r.y = fmaxf(fmaf(di, ay + gs.y, b4.y), 0.f);
        r.z = fmaxf(fmaf(di, az + gs.z, b4.z), 0.f);
        r.w = fmaxf(fmaf(di, aw + gs.w, b4.w), 0.f);
        *(float4*)(O + (size_t)i * 64 + 4 * l) = r;
    }
}

// ---------- softmax(H @ Wfc + bfc) ----------
__global__ __launch_bounds__(256) void k_fc_softmax(const float* __restrict__ H, const float* __restrict__ Wfc,
                                                    const float* __restrict__ bfc, float* __restrict__ O, int N) {
    __shared__ float wf[64 * 16];
    __shared__ float bf[16];
    int t = threadIdx.x;
    for (int k = t; k < 1024; k += 256) wf[k] = Wfc[k];
    if (t < 16) bf[t] = bfc[t];
    __syncthreads();
    int gid = blockIdx.x * 256 + t;
    int node = gid >> 4;
    int c = gid & 15;
    if (node >= N) return;
    const float4* hv = (const float4*)(H + (size_t)node * 64);
    float acc = bf[c];
    #pragma unroll
    for (int kk = 0; kk < 16; kk++) {
        float4 h4 = hv[kk];
        acc = fmaf(h4.x, wf[(4 * kk + 0) * 16 + c], acc);
        acc = fmaf(h4.y, wf[(4 * kk + 1) * 16 + c], acc);
        acc = fmaf(h4.z, wf[(4 * kk + 2) * 16 + c], acc);
        acc = fmaf(h4.w, wf[(4 * kk + 3) * 16 + c], acc);
    }
    float m = acc;
    #pragma unroll
    for (int mask = 1; mask < 16; mask <<= 1) m = fmaxf(m, __shfl_xor(m, mask));
    float ex = expf(acc - m);
    float s = ex;
    #pragma unroll
    for (int mask = 1; mask < 16; mask <<= 1) s += __shfl_xor(s, mask);
    O[(size_t)node * 16 + c] = ex / s;
}

extern "C" void kernel_launch(void* const* d_in, const int* in_sizes, int n_in,
                              void* d_out, int out_size, void* d_ws, size_t ws_size,
                              hipStream_t stream) {
    const float* x   = (const float*)d_in[0];
    const int*   ei  = (const int*)d_in[1];
    const float* W1  = (const float*)d_in[2];
    const float* b1  = (const float*)d_in[3];
    const float* W2  = (const float*)d_in[4];
    const float* b2  = (const float*)d_in[5];
    const float* Wfc = (const float*)d_in[6];
    const float* bfc = (const float*)d_in[7];
    float* out = (float*)d_out;
    const int N = NNODES;
    const int E = in_sizes[1] / 2;

    char* ws = (char*)d_ws;
    size_t off = 0;
    auto take = [&](size_t bytes) {
        char* p = ws + off;
        off = (off + bytes + 255) & ~(size_t)255;
        return p;
    };
    float* bufA    = (float*)take((size_t)N * 64 * 4);  // staging aliases bufA
    float* bufB    = (float*)take((size_t)N * 64 * 4);
    int*   ssort   = (int*)take((size_t)E * 4);
    int*   rowptr  = (int*)take((size_t)(N + 1) * 4);
    float* dinv    = (float*)take((size_t)N * 4);
    int*   bcnt    = (int*)take((size_t)(NBUCK + 1) * 4);
    int*   bptr    = (int*)take((size_t)(NBUCK + 1) * 4);
    int*   bcur    = (int*)take((size_t)NBUCK * 4);
    int*   staging = (int*)bufA;  // consumed by k_bucket_csr before transform writes bufA

    const int* e_src = ei;
    const int* e_dst = ei + E;

    hipMemsetAsync(bcnt, 0, (size_t)NBUCK * 4, stream);
    k_bhist<<<256, 256, 0, stream>>>(e_dst, bcnt, E);
    k_bscan<<<1, 1024, 0, stream>>>(bcnt, bptr, bcur, rowptr, N, E);
    int chunk = (E + 127) / 128;
    k_ms_scatter<<<128, 256, 0, stream>>>(e_src, e_dst, bcur, staging, E, chunk);
    k_bucket_csr<<<NBUCK, 256, 0, stream>>>(staging, bptr, rowptr, ssort, dinv, N);

    int tb = (N + 127) / 128;  // 782
    k_transform2<<<tb, 128, 0, stream>>>(x, W1, dinv, bufA, N);
    k_agg<<<(N + 3) / 4, 256, 0, stream>>>(bufA, rowptr, ssort, dinv, b1, bufB, N);
    k_transform2<<<tb, 128, 0, stream>>>(bufB, W2, dinv, bufA, N);
    k_agg<<<(N + 3) / 4, 256, 0, stream>>>(bufA, rowptr, ssort, dinv, b2, bufB, N);
    k_fc_softmax<<<(N * 16 + 255) / 256, 256, 0, stream>>>(bufB, Wfc, bfc, out, N);
}

// Round 8
// 253.507 us; speedup vs baseline: 6.3899x; 1.1920x over previous
//
#include <hip/hip_runtime.h>
#include <hip/hip_fp16.h>
#include <math.h>

#define NNODES 100000
#define BSHIFT 7
#define BSIZE 128
#define NBUCK ((NNODES + BSIZE - 1) >> BSHIFT)  // 782
#define SCAT_BLOCKS 128

// ---------- per-chunk bucket histogram (persisted) + global counts ----------
__global__ __launch_bounds__(256) void k_bhist(const int* __restrict__ dst, int* __restrict__ bcnt,
                                               int* __restrict__ lhout, int E, int chunk) {
    __shared__ int h[NBUCK];
    int t = threadIdx.x;
    for (int k = t; k < NBUCK; k += 256) h[k] = 0;
    __syncthreads();
    int c0 = blockIdx.x * chunk, c1 = min(E, c0 + chunk);
    for (int i = c0 + t; i < c1; i += 256)
        atomicAdd(&h[dst[i] >> BSHIFT], 1);
    __syncthreads();
    int* lh = lhout + blockIdx.x * NBUCK;
    for (int k = t; k < NBUCK; k += 256) {
        int c = h[k];
        lh[k] = c;
        if (c) atomicAdd(&bcnt[k], c);
    }
}

// ---------- scan bucket counts -> bptr/bcur; rowptr[N]=E ----------
__global__ __launch_bounds__(1024) void k_bscan(const int* __restrict__ bcnt, int* __restrict__ bptr,
                                                int* __restrict__ bcur, int* __restrict__ rowptr,
                                                int N, int E) {
    __shared__ int s[1024];
    int t = threadIdx.x;
    int v = (t < NBUCK) ? bcnt[t] : 0;
    s[t] = v;
    __syncthreads();
    #pragma unroll
    for (int off = 1; off < 1024; off <<= 1) {
        int u = (t >= off) ? s[t - off] : 0;
        __syncthreads();
        s[t] += u;
        __syncthreads();
    }
    if (t < NBUCK) {
        int ex = s[t] - v;
        bptr[t] = ex;
        bcur[t] = ex;
    }
    if (t == 0) {
        bptr[NBUCK] = E;
        rowptr[N] = E;
    }
}

// ---------- scatter using persisted histograms (one pass over edges) ----------
// staging word = (src << 7) | (dst & 127); src < 2^17 fits.
__global__ __launch_bounds__(256) void k_ms_scatter(const int* __restrict__ src, const int* __restrict__ dst,
                                                    int* __restrict__ bcur, const int* __restrict__ lhout,
                                                    int* __restrict__ staging, int E, int chunk) {
    __shared__ int lcur[NBUCK];
    int t = threadIdx.x;
    const int* lh = lhout + blockIdx.x * NBUCK;
    for (int k = t; k < NBUCK; k += 256) {
        int c = lh[k];
        lcur[k] = c ? atomicAdd(&bcur[k], c) : 0;
    }
    __syncthreads();
    int c0 = blockIdx.x * chunk, c1 = min(E, c0 + chunk);
    for (int i = c0 + t; i < c1; i += 256) {
        int d = dst[i];
        int pos = atomicAdd(&lcur[d >> BSHIFT], 1);
        staging[pos] = (src[i] << BSHIFT) | (d & (BSIZE - 1));
    }
}

// ---------- per-bucket CSR: rowptr + dinv + bucket-local ssort ----------
__global__ __launch_bounds__(256) void k_bucket_csr(const int* __restrict__ staging, const int* __restrict__ bptr,
                                                    int* __restrict__ rowptr, int* __restrict__ ssort,
                                                    float* __restrict__ dinv, int N) {
    __shared__ int lcnt[BSIZE], lpre[BSIZE];
    int b = blockIdx.x, t = threadIdx.x;
    int node0 = b << BSHIFT;
    int bbase = bptr[b], bend = bptr[b + 1];
    if (t < BSIZE) lcnt[t] = 0;
    __syncthreads();
    for (int e = bbase + t; e < bend; e += 256)
        atomicAdd(&lcnt[staging[e] & (BSIZE - 1)], 1);
    __syncthreads();
    if (t < BSIZE) lpre[t] = lcnt[t];
    __syncthreads();
    #pragma unroll
    for (int off = 1; off < BSIZE; off <<= 1) {
        int u = 0;
        if (t < BSIZE && t >= off) u = lpre[t - off];
        __syncthreads();
        if (t < BSIZE) lpre[t] += u;
        __syncthreads();
    }
    if (t < BSIZE) {
        int node = node0 + t;
        if (node < N) {
            rowptr[node] = bbase + lpre[t] - lcnt[t];
            dinv[node] = rsqrtf((float)(lcnt[t] + 1));  // +1 self-loop
        }
        lpre[t] -= lcnt[t];  // exclusive prefix -> local cursor
    }
    __syncthreads();
    for (int e = bbase + t; e < bend; e += 256) {
        int p = staging[e];
        int pos = atomicAdd(&lpre[p & (BSIZE - 1)], 1);
        ssort[bbase + pos] = p >> BSHIFT;  // writes stay in this bucket's segment
    }
}

// ---------- G(half) = dinv[i] * (X @ W), LDS-tiled, thread-per-node ----------
__global__ __launch_bounds__(128) void k_transform2(const float* __restrict__ X, const float* __restrict__ W,
                                                    const float* __restrict__ dinv, __half* __restrict__ Gh, int N) {
    __shared__ float Xs[128 * 65];
    __shared__ float Ws[64 * 64];
    int t = threadIdx.x;
    int node0 = blockIdx.x << 7;
    // stage W: 4096 floats = 1024 float4 = 8 per thread
    {
        const float4* W4 = (const float4*)W;
        float4* Ws4 = (float4*)Ws;
        #pragma unroll
        for (int j = 0; j < 8; j++) Ws4[j * 128 + t] = W4[j * 128 + t];
    }
    // stage X tile (2048 float4), coalesced; pad rows to 65 floats
    {
        const float4* X4 = (const float4*)X;
        int lim4 = N << 4;
        #pragma unroll
        for (int ii = 0; ii < 16; ii++) {
            int f = ii * 128 + t;
            int row = f >> 4, cq = f & 15;
            int gi = (node0 << 4) + f;
            float4 v = make_float4(0.f, 0.f, 0.f, 0.f);
            if (gi < lim4) v = X4[gi];
            *(float4*)&Xs[row * 65 + cq * 4] = v;
        }
    }
    __syncthreads();
    float acc[64];
    #pragma unroll
    for (int c = 0; c < 64; c++) acc[c] = 0.f;
    int xbase = t * 65;
    for (int k = 0; k < 64; k++) {
        float xk = Xs[xbase + k];           // 2-way bank alias = free
        const float4* wr = (const float4*)&Ws[k * 64];
        #pragma unroll
        for (int cb = 0; cb < 16; cb++) {
            float4 w4 = wr[cb];             // uniform -> broadcast
            acc[cb * 4 + 0] = fmaf(xk, w4.x, acc[cb * 4 + 0]);
            acc[cb * 4 + 1] = fmaf(xk, w4.y, acc[cb * 4 + 1]);
            acc[cb * 4 + 2] = fmaf(xk, w4.z, acc[cb * 4 + 2]);
            acc[cb * 4 + 3] = fmaf(xk, w4.w, acc[cb * 4 + 3]);
        }
    }
    int node = node0 + t;
    if (node < N) {
        float di = dinv[node];
        float4* g4 = (float4*)(Gh + (size_t)node * 64);  // 8 x float4-of-8-halves
        #pragma unroll
        for (int cb = 0; cb < 8; cb++) {
            float4 pack;
            __half2* hp = (__half2*)&pack;
            #pragma unroll
            for (int q = 0; q < 4; q++)
                hp[q] = __floats2half2_rn(acc[cb * 8 + 2 * q] * di, acc[cb * 8 + 2 * q + 1] * di);
            g4[cb] = pack;
        }
    }
}

// ---------- out = relu(dinv[i] * (G[i] + sum_j G[j]) + b), G in fp16 ----------
// wave per node; lane = 8*sub + l; 8 lanes x float4(8 halves) = one 128B row; 16 edges in flight.
__global__ __launch_bounds__(256) void k_agg(const __half* __restrict__ G, const int* __restrict__ rowptr,
                                             const int* __restrict__ ssort, const float* __restrict__ dinv,
                                             const float* __restrict__ bias, float* __restrict__ O, int N) {
    int lane = threadIdx.x & 63;
    int wid = threadIdx.x >> 6;
    int sub = lane >> 3;       // 0..7: edge slot
    int l = lane & 7;          // 0..7: feature octet
    int i = blockIdx.x * 4 + wid;
    if (i >= N) return;
    int beg = rowptr[i], end = rowptr[i + 1];
    float a[8] = {0.f, 0.f, 0.f, 0.f, 0.f, 0.f, 0.f, 0.f};
    int e = beg + sub;
    for (; e + 8 < end; e += 16) {
        int s0 = ssort[e];
        int s1 = ssort[e + 8];
        float4 g0 = *(const float4*)(G + (size_t)s0 * 64 + 8 * l);
        float4 g1 = *(const float4*)(G + (size_t)s1 * 64 + 8 * l);
        const __half2* h0 = (const __half2*)&g0;
        const __half2* h1 = (const __half2*)&g1;
        #pragma unroll
        for (int q = 0; q < 4; q++) {
            float2 f0 = __half22float2(h0[q]);
            float2 f1 = __half22float2(h1[q]);
            a[2 * q]     += f0.x + f1.x;
            a[2 * q + 1] += f0.y + f1.y;
        }
    }
    if (e < end) {
        int s0 = ssort[e];
        float4 g0 = *(const float4*)(G + (size_t)s0 * 64 + 8 * l);
        const __half2* h0 = (const __half2*)&g0;
        #pragma unroll
        for (int q = 0; q < 4; q++) {
            float2 f0 = __half22float2(h0[q]);
            a[2 * q]     += f0.x;
            a[2 * q + 1] += f0.y;
        }
    }
    #pragma unroll
    for (int mask = 8; mask <= 32; mask <<= 1) {
        #pragma unroll
        for (int q = 0; q < 8; q++) a[q] += __shfl_xor(a[q], mask);
    }
    if (sub == 0) {
        float4 gs = *(const float4*)(G + (size_t)i * 64 + 8 * l);
        const __half2* hs = (const __half2*)&gs;
        #pragma unroll
        for (int q = 0; q < 4; q++) {
            float2 fs = __half22float2(hs[q]);
            a[2 * q]     += fs.x;
            a[2 * q + 1] += fs.y;
        }
        float di = dinv[i];
        float4 b0 = *(const float4*)(bias + 8 * l);
        float4 b1 = *(const float4*)(bias + 8 * l + 4);
        float4 o0, o1;
        o0.x = fmaxf(fmaf(di, a[0], b0.x), 0.f);
        o0.y = fmaxf(fmaf(di, a[1], b0.y), 0.f);
        o0.z = fmaxf(fmaf(di, a[2], b0.z), 0.f);
        o0.w = fmaxf(fmaf(di, a[3], b0.w), 0.f);
        o1.x = fmaxf(fmaf(di, a[4], b1.x), 0.f);
        o1.y = fmaxf(fmaf(di, a[5], b1.y), 0.f);
        o1.z = fmaxf(fmaf(di, a[6], b1.z), 0.f);
        o1.w = fmaxf(fmaf(di, a[7], b1.w), 0.f);
        *(float4*)(O + (size_t)i * 64 + 8 * l) = o0;
        *(float4*)(O + (size_t)i * 64 + 8 * l + 4) = o1;
    }
}

// ---------- softmax(H @ Wfc + bfc) ----------
__global__ __launch_bounds__(256) void k_fc_softmax(const float* __restrict__ H, const float* __restrict__ Wfc,
                                                    const float* __restrict__ bfc, float* __restrict__ O, int N) {
    __shared__ float wf[64 * 16];
    __shared__ float bf[16];
    int t = threadIdx.x;
    for (int k = t; k < 1024; k += 256) wf[k] = Wfc[k];
    if (t < 16) bf[t] = bfc[t];
    __syncthreads();
    int gid = blockIdx.x * 256 + t;
    int node = gid >> 4;
    int c = gid & 15;
    if (node >= N) return;
    const float4* hv = (const float4*)(H + (size_t)node * 64);
    float acc = bf[c];
    #pragma unroll
    for (int kk = 0; kk < 16; kk++) {
        float4 h4 = hv[kk];
        acc = fmaf(h4.x, wf[(4 * kk + 0) * 16 + c], acc);
        acc = fmaf(h4.y, wf[(4 * kk + 1) * 16 + c], acc);
        acc = fmaf(h4.z, wf[(4 * kk + 2) * 16 + c], acc);
        acc = fmaf(h4.w, wf[(4 * kk + 3) * 16 + c], acc);
    }
    float m = acc;
    #pragma unroll
    for (int mask = 1; mask < 16; mask <<= 1) m = fmaxf(m, __shfl_xor(m, mask));
    float ex = expf(acc - m);
    float s = ex;
    #pragma unroll
    for (int mask = 1; mask < 16; mask <<= 1) s += __shfl_xor(s, mask);
    O[(size_t)node * 16 + c] = ex / s;
}

extern "C" void kernel_launch(void* const* d_in, const int* in_sizes, int n_in,
                              void* d_out, int out_size, void* d_ws, size_t ws_size,
                              hipStream_t stream) {
    const float* x   = (const float*)d_in[0];
    const int*   ei  = (const int*)d_in[1];
    const float* W1  = (const float*)d_in[2];
    const float* b1  = (const float*)d_in[3];
    const float* W2  = (const float*)d_in[4];
    const float* b2  = (const float*)d_in[5];
    const float* Wfc = (const float*)d_in[6];
    const float* bfc = (const float*)d_in[7];
    float* out = (float*)d_out;
    const int N = NNODES;
    const int E = in_sizes[1] / 2;

    char* ws = (char*)d_ws;
    size_t off = 0;
    auto take = [&](size_t bytes) {
        char* p = ws + off;
        off = (off + bytes + 255) & ~(size_t)255;
        return p;
    };
    float*  bufA    = (float*)take((size_t)N * 64 * 4);  // staging + Gh alias bufA
    float*  bufB    = (float*)take((size_t)N * 64 * 4);  // H (f32) between layers
    __half* Gh      = (__half*)take((size_t)N * 64 * 2); // fp16 G table
    int*    ssort   = (int*)take((size_t)E * 4);
    int*    rowptr  = (int*)take((size_t)(N + 1) * 4);
    float*  dinv    = (float*)take((size_t)N * 4);
    int*    bcnt    = (int*)take((size_t)(NBUCK + 1) * 4);
    int*    bptr    = (int*)take((size_t)(NBUCK + 1) * 4);
    int*    bcur    = (int*)take((size_t)NBUCK * 4);
    int*    lhout   = (int*)take((size_t)SCAT_BLOCKS * NBUCK * 4);
    int*    staging = (int*)bufA;  // consumed by k_bucket_csr before anything writes bufA

    const int* e_src = ei;
    const int* e_dst = ei + E;

    hipMemsetAsync(bcnt, 0, (size_t)NBUCK * 4, stream);
    int chunk = (E + SCAT_BLOCKS - 1) / SCAT_BLOCKS;
    k_bhist<<<SCAT_BLOCKS, 256, 0, stream>>>(e_dst, bcnt, lhout, E, chunk);
    k_bscan<<<1, 1024, 0, stream>>>(bcnt, bptr, bcur, rowptr, N, E);
    k_ms_scatter<<<SCAT_BLOCKS, 256, 0, stream>>>(e_src, e_dst, bcur, lhout, staging, E, chunk);
    k_bucket_csr<<<NBUCK, 256, 0, stream>>>(staging, bptr, rowptr, ssort, dinv, N);

    int tb = (N + 127) / 128;  // 782
    k_transform2<<<tb, 128, 0, stream>>>(x, W1, dinv, Gh, N);
    k_agg<<<(N + 3) / 4, 256, 0, stream>>>(Gh, rowptr, ssort, dinv, b1, bufB, N);
    k_transform2<<<tb, 128, 0, stream>>>(bufB, W2, dinv, Gh, N);
    k_agg<<<(N + 3) / 4, 256, 0, stream>>>(Gh, rowptr, ssort, dinv, b2, bufB, N);
    k_fc_softmax<<<(N * 16 + 255) / 256, 256, 0, stream>>>(bufB, Wfc, bfc, out, N);
}

// Round 9
// 224.463 us; speedup vs baseline: 7.2167x; 1.1294x over previous
//
#include <hip/hip_runtime.h>
#include <hip/hip_fp16.h>
#include <math.h>

#define NNODES 100000
#define BSHIFT 7
#define BSIZE 128
#define NBUCK ((NNODES + BSIZE - 1) >> BSHIFT)  // 782
#define SCAT_BLOCKS 512
#define CHUNKCAP 3328        // >= ceil(E/SCAT_BLOCKS) for E<=1.703M
#define CAPSHIFT 12          // 4096 slots per bucket segment (mean 2048 + 45 sigma)
#define BCAP (1 << CAPSHIFT)

// ---------- init fixed-capacity bucket cursors ----------
__global__ __launch_bounds__(1024) void k_init(int* __restrict__ bcur) {
    int k = blockIdx.x * 1024 + threadIdx.x;
    if (k < NBUCK) bcur[k] = k << CAPSHIFT;
}

// ---------- fused single-pass bucket scatter ----------
// LDS-stage the chunk, histogram, reserve runs (<=782 global atomics/block), scatter from LDS.
__global__ __launch_bounds__(256) void k_scatter_fused(const int* __restrict__ src, const int* __restrict__ dst,
                                                       int* __restrict__ bcur, int* __restrict__ staging,
                                                       int E, int chunk) {
    __shared__ int epack[CHUNKCAP];
    __shared__ unsigned short ebuck[CHUNKCAP];
    __shared__ int hist[NBUCK];
    __shared__ int lcur[NBUCK];
    int t = threadIdx.x;
    for (int k = t; k < NBUCK; k += 256) hist[k] = 0;
    __syncthreads();
    int c0 = blockIdx.x * chunk;
    int c1 = min(E, c0 + chunk);
    int n = c1 - c0;
    for (int j = t; j < n; j += 256) {
        int d = dst[c0 + j];
        int s = src[c0 + j];
        int b = d >> BSHIFT;
        epack[j] = (s << BSHIFT) | (d & (BSIZE - 1));
        ebuck[j] = (unsigned short)b;
        atomicAdd(&hist[b], 1);
    }
    __syncthreads();
    for (int k = t; k < NBUCK; k += 256) {
        int c = hist[k];
        lcur[k] = c ? atomicAdd(&bcur[k], c) : 0;
    }
    __syncthreads();
    for (int j = t; j < n; j += 256) {
        int pos = atomicAdd(&lcur[ebuck[j]], 1);
        staging[pos] = epack[j];
    }
}

// ---------- per-bucket CSR over padded segments: rowptr/rowend + dinv + local ssort ----------
__global__ __launch_bounds__(256) void k_bucket_csr(const int* __restrict__ staging, const int* __restrict__ bcur,
                                                    int* __restrict__ rowptr, int* __restrict__ rowend,
                                                    int* __restrict__ ssort, float* __restrict__ dinv, int N) {
    __shared__ int lcnt[BSIZE], lpre[BSIZE];
    int b = blockIdx.x, t = threadIdx.x;
    int node0 = b << BSHIFT;
    int bbase = b << CAPSHIFT;
    int bend = bcur[b];        // final cursor = bbase + count
    if (t < BSIZE) lcnt[t] = 0;
    __syncthreads();
    for (int e = bbase + t; e < bend; e += 256)
        atomicAdd(&lcnt[staging[e] & (BSIZE - 1)], 1);
    __syncthreads();
    if (t < BSIZE) lpre[t] = lcnt[t];
    __syncthreads();
    #pragma unroll
    for (int off = 1; off < BSIZE; off <<= 1) {
        int u = 0;
        if (t < BSIZE && t >= off) u = lpre[t - off];
        __syncthreads();
        if (t < BSIZE) lpre[t] += u;
        __syncthreads();
    }
    if (t < BSIZE) {
        int node = node0 + t;
        if (node < N) {
            int beg = bbase + lpre[t] - lcnt[t];
            rowptr[node] = beg;
            rowend[node] = beg + lcnt[t];
            dinv[node] = rsqrtf((float)(lcnt[t] + 1));  // +1 self-loop
        }
        lpre[t] -= lcnt[t];  // exclusive prefix -> local cursor
    }
    __syncthreads();
    for (int e = bbase + t; e < bend; e += 256) {
        int p = staging[e];
        int pos = atomicAdd(&lpre[p & (BSIZE - 1)], 1);
        ssort[bbase + pos] = p >> BSHIFT;  // writes stay in this bucket's segment
    }
}

// ---------- G(half) = dinv[i] * (X @ W), LDS-tiled, thread-per-node ----------
__global__ __launch_bounds__(128) void k_transform2(const float* __restrict__ X, const float* __restrict__ W,
                                                    const float* __restrict__ dinv, __half* __restrict__ Gh, int N) {
    __shared__ float Xs[128 * 65];
    __shared__ float Ws[64 * 64];
    int t = threadIdx.x;
    int node0 = blockIdx.x << 7;
    {
        const float4* W4 = (const float4*)W;
        float4* Ws4 = (float4*)Ws;
        #pragma unroll
        for (int j = 0; j < 8; j++) Ws4[j * 128 + t] = W4[j * 128 + t];
    }
    {
        const float4* X4 = (const float4*)X;
        int lim4 = N << 4;
        #pragma unroll
        for (int ii = 0; ii < 16; ii++) {
            int f = ii * 128 + t;
            int row = f >> 4, cq = f & 15;
            int gi = (node0 << 4) + f;
            float4 v = make_float4(0.f, 0.f, 0.f, 0.f);
            if (gi < lim4) v = X4[gi];
            *(float4*)&Xs[row * 65 + cq * 4] = v;
        }
    }
    __syncthreads();
    float acc[64];
    #pragma unroll
    for (int c = 0; c < 64; c++) acc[c] = 0.f;
    int xbase = t * 65;
    for (int k = 0; k < 64; k++) {
        float xk = Xs[xbase + k];
        const float4* wr = (const float4*)&Ws[k * 64];
        #pragma unroll
        for (int cb = 0; cb < 16; cb++) {
            float4 w4 = wr[cb];
            acc[cb * 4 + 0] = fmaf(xk, w4.x, acc[cb * 4 + 0]);
            acc[cb * 4 + 1] = fmaf(xk, w4.y, acc[cb * 4 + 1]);
            acc[cb * 4 + 2] = fmaf(xk, w4.z, acc[cb * 4 + 2]);
            acc[cb * 4 + 3] = fmaf(xk, w4.w, acc[cb * 4 + 3]);
        }
    }
    int node = node0 + t;
    if (node < N) {
        float di = dinv[node];
        float4* g4 = (float4*)(Gh + (size_t)node * 64);
        #pragma unroll
        for (int cb = 0; cb < 8; cb++) {
            float4 pack;
            __half2* hp = (__half2*)&pack;
            #pragma unroll
            for (int q = 0; q < 4; q++)
                hp[q] = __floats2half2_rn(acc[cb * 8 + 2 * q] * di, acc[cb * 8 + 2 * q + 1] * di);
            g4[cb] = pack;
        }
    }
}

// ---------- out = relu(dinv[i] * (G[i] + sum_j G[j]) + b), G in fp16 ----------
__global__ __launch_bounds__(256) void k_agg(const __half* __restrict__ G, const int* __restrict__ rowptr,
                                             const int* __restrict__ rowend, const int* __restrict__ ssort,
                                             const float* __restrict__ dinv, const float* __restrict__ bias,
                                             float* __restrict__ O, int N) {
    int lane = threadIdx.x & 63;
    int wid = threadIdx.x >> 6;
    int sub = lane >> 3;       // 0..7: edge slot
    int l = lane & 7;          // 0..7: feature octet
    int i = blockIdx.x * 4 + wid;
    if (i >= N) return;
    int beg = rowptr[i], end = rowend[i];
    float a[8] = {0.f, 0.f, 0.f, 0.f, 0.f, 0.f, 0.f, 0.f};
    int e = beg + sub;
    for (; e + 8 < end; e += 16) {
        int s0 = ssort[e];
        int s1 = ssort[e + 8];
        float4 g0 = *(const float4*)(G + (size_t)s0 * 64 + 8 * l);
        float4 g1 = *(const float4*)(G + (size_t)s1 * 64 + 8 * l);
        const __half2* h0 = (const __half2*)&g0;
        const __half2* h1 = (const __half2*)&g1;
        #pragma unroll
        for (int q = 0; q < 4; q++) {
            float2 f0 = __half22float2(h0[q]);
            float2 f1 = __half22float2(h1[q]);
            a[2 * q]     += f0.x + f1.x;
            a[2 * q + 1] += f0.y + f1.y;
        }
    }
    if (e < end) {
        int s0 = ssort[e];
        float4 g0 = *(const float4*)(G + (size_t)s0 * 64 + 8 * l);
        const __half2* h0 = (const __half2*)&g0;
        #pragma unroll
        for (int q = 0; q < 4; q++) {
            float2 f0 = __half22float2(h0[q]);
            a[2 * q]     += f0.x;
            a[2 * q + 1] += f0.y;
        }
    }
    #pragma unroll
    for (int mask = 8; mask <= 32; mask <<= 1) {
        #pragma unroll
        for (int q = 0; q < 8; q++) a[q] += __shfl_xor(a[q], mask);
    }
    if (sub == 0) {
        float4 gs = *(const float4*)(G + (size_t)i * 64 + 8 * l);
        const __half2* hs = (const __half2*)&gs;
        #pragma unroll
        for (int q = 0; q < 4; q++) {
            float2 fs = __half22float2(hs[q]);
            a[2 * q]     += fs.x;
            a[2 * q + 1] += fs.y;
        }
        float di = dinv[i];
        float4 b0 = *(const float4*)(bias + 8 * l);
        float4 b1 = *(const float4*)(bias + 8 * l + 4);
        float4 o0, o1;
        o0.x = fmaxf(fmaf(di, a[0], b0.x), 0.f);
        o0.y = fmaxf(fmaf(di, a[1], b0.y), 0.f);
        o0.z = fmaxf(fmaf(di, a[2], b0.z), 0.f);
        o0.w = fmaxf(fmaf(di, a[3], b0.w), 0.f);
        o1.x = fmaxf(fmaf(di, a[4], b1.x), 0.f);
        o1.y = fmaxf(fmaf(di, a[5], b1.y), 0.f);
        o1.z = fmaxf(fmaf(di, a[6], b1.z), 0.f);
        o1.w = fmaxf(fmaf(di, a[7], b1.w), 0.f);
        *(float4*)(O + (size_t)i * 64 + 8 * l) = o0;
        *(float4*)(O + (size_t)i * 64 + 8 * l + 4) = o1;
    }
}

// ---------- softmax(H @ Wfc + bfc) ----------
__global__ __launch_bounds__(256) void k_fc_softmax(const float* __restrict__ H, const float* __restrict__ Wfc,
                                                    const float* __restrict__ bfc, float* __restrict__ O, int N) {
    __shared__ float wf[64 * 16];
    __shared__ float bf[16];
    int t = threadIdx.x;
    for (int k = t; k < 1024; k += 256) wf[k] = Wfc[k];
    if (t < 16) bf[t] = bfc[t];
    __syncthreads();
    int gid = blockIdx.x * 256 + t;
    int node = gid >> 4;
    int c = gid & 15;
    if (node >= N) return;
    const float4* hv = (const float4*)(H + (size_t)node * 64);
    float acc = bf[c];
    #pragma unroll
    for (int kk = 0; kk < 16; kk++) {
        float4 h4 = hv[kk];
        acc = fmaf(h4.x, wf[(4 * kk + 0) * 16 + c], acc);
        acc = fmaf(h4.y, wf[(4 * kk + 1) * 16 + c], acc);
        acc = fmaf(h4.z, wf[(4 * kk + 2) * 16 + c], acc);
        acc = fmaf(h4.w, wf[(4 * kk + 3) * 16 + c], acc);
    }
    float m = acc;
    #pragma unroll
    for (int mask = 1; mask < 16; mask <<= 1) m = fmaxf(m, __shfl_xor(m, mask));
    float ex = expf(acc - m);
    float s = ex;
    #pragma unroll
    for (int mask = 1; mask < 16; mask <<= 1) s += __shfl_xor(s, mask);
    O[(size_t)node * 16 + c] = ex / s;
}

extern "C" void kernel_launch(void* const* d_in, const int* in_sizes, int n_in,
                              void* d_out, int out_size, void* d_ws, size_t ws_size,
                              hipStream_t stream) {
    const float* x   = (const float*)d_in[0];
    const int*   ei  = (const int*)d_in[1];
    const float* W1  = (const float*)d_in[2];
    const float* b1  = (const float*)d_in[3];
    const float* W2  = (const float*)d_in[4];
    const float* b2  = (const float*)d_in[5];
    const float* Wfc = (const float*)d_in[6];
    const float* bfc = (const float*)d_in[7];
    float* out = (float*)d_out;
    const int N = NNODES;
    const int E = in_sizes[1] / 2;

    char* ws = (char*)d_ws;
    size_t off = 0;
    auto take = [&](size_t bytes) {
        char* p = ws + off;
        off = (off + bytes + 255) & ~(size_t)255;
        return p;
    };
    int*    staging = (int*)take((size_t)NBUCK * BCAP * 4);   // 12.8 MB padded segments
    int*    ssort   = (int*)take((size_t)NBUCK * BCAP * 4);   // 12.8 MB padded segments
    float*  bufB    = (float*)take((size_t)N * 64 * 4);       // H (f32) between layers
    __half* Gh      = (__half*)take((size_t)N * 64 * 2);      // fp16 G table
    int*    rowptr  = (int*)take((size_t)N * 4);
    int*    rowend  = (int*)take((size_t)N * 4);
    float*  dinv    = (float*)take((size_t)N * 4);
    int*    bcur    = (int*)take((size_t)NBUCK * 4);

    const int* e_src = ei;
    const int* e_dst = ei + E;

    int chunk = (E + SCAT_BLOCKS - 1) / SCAT_BLOCKS;  // 3125 for E=1.6M (<= CHUNKCAP)
    k_init<<<1, 1024, 0, stream>>>(bcur);
    k_scatter_fused<<<SCAT_BLOCKS, 256, 0, stream>>>(e_src, e_dst, bcur, staging, E, chunk);
    k_bucket_csr<<<NBUCK, 256, 0, stream>>>(staging, bcur, rowptr, rowend, ssort, dinv, N);

    int tb = (N + 127) / 128;  // 782
    k_transform2<<<tb, 128, 0, stream>>>(x, W1, dinv, Gh, N);
    k_agg<<<(N + 3) / 4, 256, 0, stream>>>(Gh, rowptr, rowend, ssort, dinv, b1, bufB, N);
    k_transform2<<<tb, 128, 0, stream>>>(bufB, W2, dinv, Gh, N);
    k_agg<<<(N + 3) / 4, 256, 0, stream>>>(Gh, rowptr, rowend, ssort, dinv, b2, bufB, N);
    k_fc_softmax<<<(N * 16 + 255) / 256, 256, 0, stream>>>(bufB, Wfc, bfc, out, N);
}

// Round 10
// 210.543 us; speedup vs baseline: 7.6939x; 1.0661x over previous
//
#include <hip/hip_runtime.h>
#include <hip/hip_fp16.h>
#include <math.h>

#define NNODES 100000
#define BSHIFT 7
#define BSIZE 128
#define NBUCK ((NNODES + BSIZE - 1) >> BSHIFT)  // 782
#define SCAT_BLOCKS 512
#define CHUNKCAP 3328        // >= ceil(E/SCAT_BLOCKS) for E<=1.703M
#define CAPSHIFT 12          // 4096 slots per bucket segment
#define BCAP (1 << CAPSHIFT)

// ---------- init fixed-capacity bucket cursors ----------
__global__ __launch_bounds__(1024) void k_init(int* __restrict__ bcur) {
    int k = blockIdx.x * 1024 + threadIdx.x;
    if (k < NBUCK) bcur[k] = k << CAPSHIFT;
}

// ---------- fused single-pass bucket scatter ----------
__global__ __launch_bounds__(256) void k_scatter_fused(const int* __restrict__ src, const int* __restrict__ dst,
                                                       int* __restrict__ bcur, int* __restrict__ staging,
                                                       int E, int chunk) {
    __shared__ int epack[CHUNKCAP];
    __shared__ unsigned short ebuck[CHUNKCAP];
    __shared__ int hist[NBUCK];
    __shared__ int lcur[NBUCK];
    int t = threadIdx.x;
    for (int k = t; k < NBUCK; k += 256) hist[k] = 0;
    __syncthreads();
    int c0 = blockIdx.x * chunk;
    int c1 = min(E, c0 + chunk);
    int n = c1 - c0;
    for (int j = t; j < n; j += 256) {
        int d = dst[c0 + j];
        int s = src[c0 + j];
        int b = d >> BSHIFT;
        epack[j] = (s << BSHIFT) | (d & (BSIZE - 1));
        ebuck[j] = (unsigned short)b;
        atomicAdd(&hist[b], 1);
    }
    __syncthreads();
    for (int k = t; k < NBUCK; k += 256) {
        int c = hist[k];
        lcur[k] = c ? atomicAdd(&bcur[k], c) : 0;
    }
    __syncthreads();
    for (int j = t; j < n; j += 256) {
        int pos = atomicAdd(&lcur[ebuck[j]], 1);
        staging[pos] = epack[j];
    }
}

// ---------- per-bucket CSR over padded segments ----------
__global__ __launch_bounds__(256) void k_bucket_csr(const int* __restrict__ staging, const int* __restrict__ bcur,
                                                    int* __restrict__ rowptr, int* __restrict__ rowend,
                                                    int* __restrict__ ssort, float* __restrict__ dinv, int N) {
    __shared__ int lcnt[BSIZE], lpre[BSIZE];
    int b = blockIdx.x, t = threadIdx.x;
    int node0 = b << BSHIFT;
    int bbase = b << CAPSHIFT;
    int bend = bcur[b];
    if (t < BSIZE) lcnt[t] = 0;
    __syncthreads();
    for (int e = bbase + t; e < bend; e += 256)
        atomicAdd(&lcnt[staging[e] & (BSIZE - 1)], 1);
    __syncthreads();
    if (t < BSIZE) lpre[t] = lcnt[t];
    __syncthreads();
    #pragma unroll
    for (int off = 1; off < BSIZE; off <<= 1) {
        int u = 0;
        if (t < BSIZE && t >= off) u = lpre[t - off];
        __syncthreads();
        if (t < BSIZE) lpre[t] += u;
        __syncthreads();
    }
    if (t < BSIZE) {
        int node = node0 + t;
        if (node < N) {
            int beg = bbase + lpre[t] - lcnt[t];
            rowptr[node] = beg;
            rowend[node] = beg + lcnt[t];
            dinv[node] = rsqrtf((float)(lcnt[t] + 1));  // +1 self-loop
        }
        lpre[t] -= lcnt[t];
    }
    __syncthreads();
    for (int e = bbase + t; e < bend; e += 256) {
        int p = staging[e];
        int pos = atomicAdd(&lpre[p & (BSIZE - 1)], 1);
        ssort[bbase + pos] = p >> BSHIFT;
    }
}

// ---------- G(half) = dinv[i] * (X @ W): W in VGPRs, X broadcast from LDS ----------
// 256 threads = 4 waves; block handles 128 nodes (32/wave); lane c owns W[:,c].
__global__ __launch_bounds__(256) void k_transform3(const float* __restrict__ X, const float* __restrict__ W,
                                                    const float* __restrict__ dinv, __half* __restrict__ Gh, int N) {
    __shared__ float4 Xs[2048];     // 128 nodes x 64 floats, linear (reads are uniform broadcasts)
    __shared__ float dinvs[128];
    int t = threadIdx.x;
    int lane = t & 63;
    int node0 = blockIdx.x << 7;
    // stage X tile: 2048 float4, coalesced, zero-filled at tail
    {
        const float4* X4 = (const float4*)X;
        int lim4 = N << 4;
        int gbase = node0 << 4;
        #pragma unroll
        for (int j = 0; j < 8; j++) {
            int f = j * 256 + t;
            int gi = gbase + f;
            Xs[f] = (gi < lim4) ? X4[gi] : make_float4(0.f, 0.f, 0.f, 0.f);
        }
    }
    if (t < 128) {
        int nd = node0 + t;
        dinvs[t] = (nd < N) ? dinv[nd] : 0.f;
    }
    // W column into VGPRs: w[k] = W[k][lane], coalesced per k
    float w[64];
    #pragma unroll
    for (int k = 0; k < 64; k++) w[k] = W[k * 64 + lane];
    __syncthreads();
    int woff = (t >> 6) * 32;   // this wave's node offset in the tile
    for (int nn = 0; nn < 32; nn += 4) {
        const float4* r0 = &Xs[(woff + nn + 0) * 16];
        const float4* r1 = &Xs[(woff + nn + 1) * 16];
        const float4* r2 = &Xs[(woff + nn + 2) * 16];
        const float4* r3 = &Xs[(woff + nn + 3) * 16];
        float a0 = 0.f, a1 = 0.f, a2 = 0.f, a3 = 0.f;
        #pragma unroll
        for (int kq = 0; kq < 16; kq++) {
            float4 xa = r0[kq];   // uniform address -> LDS broadcast, no conflict
            float4 xb = r1[kq];
            float4 xc = r2[kq];
            float4 xd = r3[kq];
            a0 = fmaf(xa.x, w[4*kq+0], a0); a0 = fmaf(xa.y, w[4*kq+1], a0);
            a0 = fmaf(xa.z, w[4*kq+2], a0); a0 = fmaf(xa.w, w[4*kq+3], a0);
            a1 = fmaf(xb.x, w[4*kq+0], a1); a1 = fmaf(xb.y, w[4*kq+1], a1);
            a1 = fmaf(xb.z, w[4*kq+2], a1); a1 = fmaf(xb.w, w[4*kq+3], a1);
            a2 = fmaf(xc.x, w[4*kq+0], a2); a2 = fmaf(xc.y, w[4*kq+1], a2);
            a2 = fmaf(xc.z, w[4*kq+2], a2); a2 = fmaf(xc.w, w[4*kq+3], a2);
            a3 = fmaf(xd.x, w[4*kq+0], a3); a3 = fmaf(xd.y, w[4*kq+1], a3);
            a3 = fmaf(xd.z, w[4*kq+2], a3); a3 = fmaf(xd.w, w[4*kq+3], a3);
        }
        int nb = node0 + woff + nn;
        float d0 = dinvs[woff+nn+0], d1 = dinvs[woff+nn+1];
        float d2 = dinvs[woff+nn+2], d3 = dinvs[woff+nn+3];
        if (nb + 3 < N) {
            Gh[(size_t)(nb+0)*64 + lane] = __float2half(a0 * d0);
            Gh[(size_t)(nb+1)*64 + lane] = __float2half(a1 * d1);
            Gh[(size_t)(nb+2)*64 + lane] = __float2half(a2 * d2);
            Gh[(size_t)(nb+3)*64 + lane] = __float2half(a3 * d3);
        } else {
            if (nb+0 < N) Gh[(size_t)(nb+0)*64 + lane] = __float2half(a0 * d0);
            if (nb+1 < N) Gh[(size_t)(nb+1)*64 + lane] = __float2half(a1 * d1);
            if (nb+2 < N) Gh[(size_t)(nb+2)*64 + lane] = __float2half(a2 * d2);
            if (nb+3 < N) Gh[(size_t)(nb+3)*64 + lane] = __float2half(a3 * d3);
        }
    }
}

// ---------- out = relu(dinv[i] * (G[i] + sum_j G[j]) + b), G in fp16 ----------
__global__ __launch_bounds__(256) void k_agg(const __half* __restrict__ G, const int* __restrict__ rowptr,
                                             const int* __restrict__ rowend, const int* __restrict__ ssort,
                                             const float* __restrict__ dinv, const float* __restrict__ bias,
                                             float* __restrict__ O, int N) {
    int lane = threadIdx.x & 63;
    int wid = threadIdx.x >> 6;
    int sub = lane >> 3;       // 0..7: edge slot
    int l = lane & 7;          // 0..7: feature octet
    int i = blockIdx.x * 4 + wid;
    if (i >= N) return;
    int beg = rowptr[i], end = rowend[i];
    float a[8] = {0.f, 0.f, 0.f, 0.f, 0.f, 0.f, 0.f, 0.f};
    int e = beg + sub;
    for (; e + 8 < end; e += 16) {
        int s0 = ssort[e];
        int s1 = ssort[e + 8];
        float4 g0 = *(const float4*)(G + (size_t)s0 * 64 + 8 * l);
        float4 g1 = *(const float4*)(G + (size_t)s1 * 64 + 8 * l);
        const __half2* h0 = (const __half2*)&g0;
        const __half2* h1 = (const __half2*)&g1;
        #pragma unroll
        for (int q = 0; q < 4; q++) {
            float2 f0 = __half22float2(h0[q]);
            float2 f1 = __half22float2(h1[q]);
            a[2 * q]     += f0.x + f1.x;
            a[2 * q + 1] += f0.y + f1.y;
        }
    }
    if (e < end) {
        int s0 = ssort[e];
        float4 g0 = *(const float4*)(G + (size_t)s0 * 64 + 8 * l);
        const __half2* h0 = (const __half2*)&g0;
        #pragma unroll
        for (int q = 0; q < 4; q++) {
            float2 f0 = __half22float2(h0[q]);
            a[2 * q]     += f0.x;
            a[2 * q + 1] += f0.y;
        }
    }
    #pragma unroll
    for (int mask = 8; mask <= 32; mask <<= 1) {
        #pragma unroll
        for (int q = 0; q < 8; q++) a[q] += __shfl_xor(a[q], mask);
    }
    if (sub == 0) {
        float4 gs = *(const float4*)(G + (size_t)i * 64 + 8 * l);
        const __half2* hs = (const __half2*)&gs;
        #pragma unroll
        for (int q = 0; q < 4; q++) {
            float2 fs = __half22float2(hs[q]);
            a[2 * q]     += fs.x;
            a[2 * q + 1] += fs.y;
        }
        float di = dinv[i];
        float4 b0 = *(const float4*)(bias + 8 * l);
        float4 b1 = *(const float4*)(bias + 8 * l + 4);
        float4 o0, o1;
        o0.x = fmaxf(fmaf(di, a[0], b0.x), 0.f);
        o0.y = fmaxf(fmaf(di, a[1], b0.y), 0.f);
        o0.z = fmaxf(fmaf(di, a[2], b0.z), 0.f);
        o0.w = fmaxf(fmaf(di, a[3], b0.w), 0.f);
        o1.x = fmaxf(fmaf(di, a[4], b1.x), 0.f);
        o1.y = fmaxf(fmaf(di, a[5], b1.y), 0.f);
        o1.z = fmaxf(fmaf(di, a[6], b1.z), 0.f);
        o1.w = fmaxf(fmaf(di, a[7], b1.w), 0.f);
        *(float4*)(O + (size_t)i * 64 + 8 * l) = o0;
        *(float4*)(O + (size_t)i * 64 + 8 * l + 4) = o1;
    }
}

// ---------- softmax(H @ Wfc + bfc) ----------
__global__ __launch_bounds__(256) void k_fc_softmax(const float* __restrict__ H, const float* __restrict__ Wfc,
                                                    const float* __restrict__ bfc, float* __restrict__ O, int N) {
    __shared__ float wf[64 * 16];
    __shared__ float bf[16];
    int t = threadIdx.x;
    for (int k = t; k < 1024; k += 256) wf[k] = Wfc[k];
    if (t < 16) bf[t] = bfc[t];
    __syncthreads();
    int gid = blockIdx.x * 256 + t;
    int node = gid >> 4;
    int c = gid & 15;
    if (node >= N) return;
    const float4* hv = (const float4*)(H + (size_t)node * 64);
    float acc = bf[c];
    #pragma unroll
    for (int kk = 0; kk < 16; kk++) {
        float4 h4 = hv[kk];
        acc = fmaf(h4.x, wf[(4 * kk + 0) * 16 + c], acc);
        acc = fmaf(h4.y, wf[(4 * kk + 1) * 16 + c], acc);
        acc = fmaf(h4.z, wf[(4 * kk + 2) * 16 + c], acc);
        acc = fmaf(h4.w, wf[(4 * kk + 3) * 16 + c], acc);
    }
    float m = acc;
    #pragma unroll
    for (int mask = 1; mask < 16; mask <<= 1) m = fmaxf(m, __shfl_xor(m, mask));
    float ex = expf(acc - m);
    float s = ex;
    #pragma unroll
    for (int mask = 1; mask < 16; mask <<= 1) s += __shfl_xor(s, mask);
    O[(size_t)node * 16 + c] = ex / s;
}

extern "C" void kernel_launch(void* const* d_in, const int* in_sizes, int n_in,
                              void* d_out, int out_size, void* d_ws, size_t ws_size,
                              hipStream_t stream) {
    const float* x   = (const float*)d_in[0];
    const int*   ei  = (const int*)d_in[1];
    const float* W1  = (const float*)d_in[2];
    const float* b1  = (const float*)d_in[3];
    const float* W2  = (const float*)d_in[4];
    const float* b2  = (const float*)d_in[5];
    const float* Wfc = (const float*)d_in[6];
    const float* bfc = (const float*)d_in[7];
    float* out = (float*)d_out;
    const int N = NNODES;
    const int E = in_sizes[1] / 2;

    char* ws = (char*)d_ws;
    size_t off = 0;
    auto take = [&](size_t bytes) {
        char* p = ws + off;
        off = (off + bytes + 255) & ~(size_t)255;
        return p;
    };
    int*    staging = (int*)take((size_t)NBUCK * BCAP * 4);   // 12.8 MB padded segments
    int*    ssort   = (int*)take((size_t)NBUCK * BCAP * 4);   // 12.8 MB padded segments
    float*  bufB    = (float*)take((size_t)N * 64 * 4);       // H (f32) between layers
    __half* Gh      = (__half*)take((size_t)N * 64 * 2);      // fp16 G table
    int*    rowptr  = (int*)take((size_t)N * 4);
    int*    rowend  = (int*)take((size_t)N * 4);
    float*  dinv    = (float*)take((size_t)N * 4);
    int*    bcur    = (int*)take((size_t)NBUCK * 4);

    const int* e_src = ei;
    const int* e_dst = ei + E;

    int chunk = (E + SCAT_BLOCKS - 1) / SCAT_BLOCKS;  // 3125 for E=1.6M
    k_init<<<1, 1024, 0, stream>>>(bcur);
    k_scatter_fused<<<SCAT_BLOCKS, 256, 0, stream>>>(e_src, e_dst, bcur, staging, E, chunk);
    k_bucket_csr<<<NBUCK, 256, 0, stream>>>(staging, bcur, rowptr, rowend, ssort, dinv, N);

    int tb = (N + 127) / 128;  // 782
    k_transform3<<<tb, 256, 0, stream>>>(x, W1, dinv, Gh, N);
    k_agg<<<(N + 3) / 4, 256, 0, stream>>>(Gh, rowptr, rowend, ssort, dinv, b1, bufB, N);
    k_transform3<<<tb, 256, 0, stream>>>(bufB, W2, dinv, Gh, N);
    k_agg<<<(N + 3) / 4, 256, 0, stream>>>(Gh, rowptr, rowend, ssort, dinv, b2, bufB, N);
    k_fc_softmax<<<(N * 16 + 255) / 256, 256, 0, stream>>>(bufB, Wfc, bfc, out, N);
}

// Round 11
// 210.386 us; speedup vs baseline: 7.6996x; 1.0007x over previous
//
#include <hip/hip_runtime.h>
#include <hip/hip_fp16.h>
#include <math.h>

#define NNODES 100000
#define BSHIFT 7
#define BSIZE 128
#define NBUCK ((NNODES + BSIZE - 1) >> BSHIFT)  // 782
#define SCAT_BLOCKS 512
#define CHUNKCAP 3328        // >= ceil(E/SCAT_BLOCKS) for E<=1.703M
#define CAPSHIFT 12          // 4096 slots per bucket segment
#define BCAP (1 << CAPSHIFT)

// ---------- init fixed-capacity bucket cursors ----------
__global__ __launch_bounds__(1024) void k_init(int* __restrict__ bcur) {
    int k = blockIdx.x * 1024 + threadIdx.x;
    if (k < NBUCK) bcur[k] = k << CAPSHIFT;
}

// ---------- fused single-pass bucket scatter ----------
__global__ __launch_bounds__(256) void k_scatter_fused(const int* __restrict__ src, const int* __restrict__ dst,
                                                       int* __restrict__ bcur, int* __restrict__ staging,
                                                       int E, int chunk) {
    __shared__ int epack[CHUNKCAP];
    __shared__ unsigned short ebuck[CHUNKCAP];
    __shared__ int hist[NBUCK];
    __shared__ int lcur[NBUCK];
    int t = threadIdx.x;
    for (int k = t; k < NBUCK; k += 256) hist[k] = 0;
    __syncthreads();
    int c0 = blockIdx.x * chunk;
    int c1 = min(E, c0 + chunk);
    int n = c1 - c0;
    for (int j = t; j < n; j += 256) {
        int d = dst[c0 + j];
        int s = src[c0 + j];
        int b = d >> BSHIFT;
        epack[j] = (s << BSHIFT) | (d & (BSIZE - 1));
        ebuck[j] = (unsigned short)b;
        atomicAdd(&hist[b], 1);
    }
    __syncthreads();
    for (int k = t; k < NBUCK; k += 256) {
        int c = hist[k];
        lcur[k] = c ? atomicAdd(&bcur[k], c) : 0;
    }
    __syncthreads();
    for (int j = t; j < n; j += 256) {
        int pos = atomicAdd(&lcur[ebuck[j]], 1);
        staging[pos] = epack[j];
    }
}

// ---------- per-bucket CSR over padded segments; ssoff = src byte-offset ----------
__global__ __launch_bounds__(256) void k_bucket_csr(const int* __restrict__ staging, const int* __restrict__ bcur,
                                                    int* __restrict__ rowptr, int* __restrict__ rowend,
                                                    int* __restrict__ ssoff, float* __restrict__ dinv, int N) {
    __shared__ int lcnt[BSIZE], lpre[BSIZE];
    int b = blockIdx.x, t = threadIdx.x;
    int node0 = b << BSHIFT;
    int bbase = b << CAPSHIFT;
    int bend = bcur[b];
    if (t < BSIZE) lcnt[t] = 0;
    __syncthreads();
    for (int e = bbase + t; e < bend; e += 256)
        atomicAdd(&lcnt[staging[e] & (BSIZE - 1)], 1);
    __syncthreads();
    if (t < BSIZE) lpre[t] = lcnt[t];
    __syncthreads();
    #pragma unroll
    for (int off = 1; off < BSIZE; off <<= 1) {
        int u = 0;
        if (t < BSIZE && t >= off) u = lpre[t - off];
        __syncthreads();
        if (t < BSIZE) lpre[t] += u;
        __syncthreads();
    }
    if (t < BSIZE) {
        int node = node0 + t;
        if (node < N) {
            int beg = bbase + lpre[t] - lcnt[t];
            rowptr[node] = beg;
            rowend[node] = beg + lcnt[t];
            dinv[node] = rsqrtf((float)(lcnt[t] + 1));  // +1 self-loop
        }
        lpre[t] -= lcnt[t];
    }
    __syncthreads();
    for (int e = bbase + t; e < bend; e += 256) {
        int p = staging[e];
        int pos = atomicAdd(&lpre[p & (BSIZE - 1)], 1);
        ssoff[bbase + pos] = (p >> BSHIFT) << 7;  // Gh row byte offset (row = 128 B)
    }
}

// ---------- G(half) = dinv[i] * (X @ W): W in VGPRs, X broadcast from LDS ----------
__global__ __launch_bounds__(256) void k_transform3(const float* __restrict__ X, const float* __restrict__ W,
                                                    const float* __restrict__ dinv, __half* __restrict__ Gh, int N) {
    __shared__ float4 Xs[2048];
    __shared__ float dinvs[128];
    int t = threadIdx.x;
    int lane = t & 63;
    int node0 = blockIdx.x << 7;
    {
        const float4* X4 = (const float4*)X;
        int lim4 = N << 4;
        int gbase = node0 << 4;
        #pragma unroll
        for (int j = 0; j < 8; j++) {
            int f = j * 256 + t;
            int gi = gbase + f;
            Xs[f] = (gi < lim4) ? X4[gi] : make_float4(0.f, 0.f, 0.f, 0.f);
        }
    }
    if (t < 128) {
        int nd = node0 + t;
        dinvs[t] = (nd < N) ? dinv[nd] : 0.f;
    }
    float w[64];
    #pragma unroll
    for (int k = 0; k < 64; k++) w[k] = W[k * 64 + lane];
    __syncthreads();
    int woff = (t >> 6) * 32;
    for (int nn = 0; nn < 32; nn += 4) {
        const float4* r0 = &Xs[(woff + nn + 0) * 16];
        const float4* r1 = &Xs[(woff + nn + 1) * 16];
        const float4* r2 = &Xs[(woff + nn + 2) * 16];
        const float4* r3 = &Xs[(woff + nn + 3) * 16];
        float a0 = 0.f, a1 = 0.f, a2 = 0.f, a3 = 0.f;
        #pragma unroll
        for (int kq = 0; kq < 16; kq++) {
            float4 xa = r0[kq];
            float4 xb = r1[kq];
            float4 xc = r2[kq];
            float4 xd = r3[kq];
            a0 = fmaf(xa.x, w[4*kq+0], a0); a0 = fmaf(xa.y, w[4*kq+1], a0);
            a0 = fmaf(xa.z, w[4*kq+2], a0); a0 = fmaf(xa.w, w[4*kq+3], a0);
            a1 = fmaf(xb.x, w[4*kq+0], a1); a1 = fmaf(xb.y, w[4*kq+1], a1);
            a1 = fmaf(xb.z, w[4*kq+2], a1); a1 = fmaf(xb.w, w[4*kq+3], a1);
            a2 = fmaf(xc.x, w[4*kq+0], a2); a2 = fmaf(xc.y, w[4*kq+1], a2);
            a2 = fmaf(xc.z, w[4*kq+2], a2); a2 = fmaf(xc.w, w[4*kq+3], a2);
            a3 = fmaf(xd.x, w[4*kq+0], a3); a3 = fmaf(xd.y, w[4*kq+1], a3);
            a3 = fmaf(xd.z, w[4*kq+2], a3); a3 = fmaf(xd.w, w[4*kq+3], a3);
        }
        int nb = node0 + woff + nn;
        float d0 = dinvs[woff+nn+0], d1 = dinvs[woff+nn+1];
        float d2 = dinvs[woff+nn+2], d3 = dinvs[woff+nn+3];
        if (nb + 3 < N) {
            Gh[(size_t)(nb+0)*64 + lane] = __float2half(a0 * d0);
            Gh[(size_t)(nb+1)*64 + lane] = __float2half(a1 * d1);
            Gh[(size_t)(nb+2)*64 + lane] = __float2half(a2 * d2);
            Gh[(size_t)(nb+3)*64 + lane] = __float2half(a3 * d3);
        } else {
            if (nb+0 < N) Gh[(size_t)(nb+0)*64 + lane] = __float2half(a0 * d0);
            if (nb+1 < N) Gh[(size_t)(nb+1)*64 + lane] = __float2half(a1 * d1);
            if (nb+2 < N) Gh[(size_t)(nb+2)*64 + lane] = __float2half(a2 * d2);
            if (nb+3 < N) Gh[(size_t)(nb+3)*64 + lane] = __float2half(a3 * d3);
        }
    }
}

// ---------- out = relu(dinv[i] * (G[i] + sum_j G[j]) + b), G fp16, byte-offset edges ----------
__global__ __launch_bounds__(256) void k_agg(const __half* __restrict__ G, const int* __restrict__ rowptr,
                                             const int* __restrict__ rowend, const int* __restrict__ ssoff,
                                             const float* __restrict__ dinv, const float* __restrict__ bias,
                                             float* __restrict__ O, int N) {
    int lane = threadIdx.x & 63;
    int wid = threadIdx.x >> 6;
    int sub = lane >> 3;       // 0..7: edge slot
    int l = lane & 7;          // 0..7: feature octet
    int i = blockIdx.x * 4 + wid;
    if (i >= N) return;
    const char* Gb = (const char*)G;
    int loff = l << 4;
    int beg = rowptr[i], end = rowend[i];
    float a[8] = {0.f, 0.f, 0.f, 0.f, 0.f, 0.f, 0.f, 0.f};
    int e = beg + sub;
    // 16 edges in flight (2 per sub), fp16 pair pre-sum then f32 accumulate
    for (; e + 8 < end; e += 16) {
        int o0 = ssoff[e];
        int o1 = ssoff[e + 8];
        float4 g0 = *(const float4*)(Gb + o0 + loff);
        float4 g1 = *(const float4*)(Gb + o1 + loff);
        const __half2* h0 = (const __half2*)&g0;
        const __half2* h1 = (const __half2*)&g1;
        #pragma unroll
        for (int q = 0; q < 4; q++) {
            __half2 s = __hadd2(h0[q], h1[q]);    // v_pk_add_f16
            float2 f = __half22float2(s);
            a[2 * q]     += f.x;
            a[2 * q + 1] += f.y;
        }
    }
    if (e < end) {
        int o0 = ssoff[e];
        float4 g0 = *(const float4*)(Gb + o0 + loff);
        const __half2* h0 = (const __half2*)&g0;
        #pragma unroll
        for (int q = 0; q < 4; q++) {
            float2 f0 = __half22float2(h0[q]);
            a[2 * q]     += f0.x;
            a[2 * q + 1] += f0.y;
        }
    }
    #pragma unroll
    for (int mask = 8; mask <= 32; mask <<= 1) {
        #pragma unroll
        for (int q = 0; q < 8; q++) a[q] += __shfl_xor(a[q], mask);
    }
    if (sub == 0) {
        float4 gs = *(const float4*)(Gb + (i << 7) + loff);
        const __half2* hs = (const __half2*)&gs;
        #pragma unroll
        for (int q = 0; q < 4; q++) {
            float2 fs = __half22float2(hs[q]);
            a[2 * q]     += fs.x;
            a[2 * q + 1] += fs.y;
        }
        float di = dinv[i];
        float4 b0 = *(const float4*)(bias + 8 * l);
        float4 b1 = *(const float4*)(bias + 8 * l + 4);
        float4 o0v, o1v;
        o0v.x = fmaxf(fmaf(di, a[0], b0.x), 0.f);
        o0v.y = fmaxf(fmaf(di, a[1], b0.y), 0.f);
        o0v.z = fmaxf(fmaf(di, a[2], b0.z), 0.f);
        o0v.w = fmaxf(fmaf(di, a[3], b0.w), 0.f);
        o1v.x = fmaxf(fmaf(di, a[4], b1.x), 0.f);
        o1v.y = fmaxf(fmaf(di, a[5], b1.y), 0.f);
        o1v.z = fmaxf(fmaf(di, a[6], b1.z), 0.f);
        o1v.w = fmaxf(fmaf(di, a[7], b1.w), 0.f);
        *(float4*)(O + (size_t)i * 64 + 8 * l) = o0v;
        *(float4*)(O + (size_t)i * 64 + 8 * l + 4) = o1v;
    }
}

// ---------- softmax(H @ Wfc + bfc) ----------
__global__ __launch_bounds__(256) void k_fc_softmax(const float* __restrict__ H, const float* __restrict__ Wfc,
                                                    const float* __restrict__ bfc, float* __restrict__ O, int N) {
    __shared__ float wf[64 * 16];
    __shared__ float bf[16];
    int t = threadIdx.x;
    for (int k = t; k < 1024; k += 256) wf[k] = Wfc[k];
    if (t < 16) bf[t] = bfc[t];
    __syncthreads();
    int gid = blockIdx.x * 256 + t;
    int node = gid >> 4;
    int c = gid & 15;
    if (node >= N) return;
    const float4* hv = (const float4*)(H + (size_t)node * 64);
    float acc = bf[c];
    #pragma unroll
    for (int kk = 0; kk < 16; kk++) {
        float4 h4 = hv[kk];
        acc = fmaf(h4.x, wf[(4 * kk + 0) * 16 + c], acc);
        acc = fmaf(h4.y, wf[(4 * kk + 1) * 16 + c], acc);
        acc = fmaf(h4.z, wf[(4 * kk + 2) * 16 + c], acc);
        acc = fmaf(h4.w, wf[(4 * kk + 3) * 16 + c], acc);
    }
    float m = acc;
    #pragma unroll
    for (int mask = 1; mask < 16; mask <<= 1) m = fmaxf(m, __shfl_xor(m, mask));
    float ex = expf(acc - m);
    float s = ex;
    #pragma unroll
    for (int mask = 1; mask < 16; mask <<= 1) s += __shfl_xor(s, mask);
    O[(size_t)node * 16 + c] = ex / s;
}

extern "C" void kernel_launch(void* const* d_in, const int* in_sizes, int n_in,
                              void* d_out, int out_size, void* d_ws, size_t ws_size,
                              hipStream_t stream) {
    const float* x   = (const float*)d_in[0];
    const int*   ei  = (const int*)d_in[1];
    const float* W1  = (const float*)d_in[2];
    const float* b1  = (const float*)d_in[3];
    const float* W2  = (const float*)d_in[4];
    const float* b2  = (const float*)d_in[5];
    const float* Wfc = (const float*)d_in[6];
    const float* bfc = (const float*)d_in[7];
    float* out = (float*)d_out;
    const int N = NNODES;
    const int E = in_sizes[1] / 2;

    char* ws = (char*)d_ws;
    size_t off = 0;
    auto take = [&](size_t bytes) {
        char* p = ws + off;
        off = (off + bytes + 255) & ~(size_t)255;
        return p;
    };
    int*    staging = (int*)take((size_t)NBUCK * BCAP * 4);
    int*    ssoff   = (int*)take((size_t)NBUCK * BCAP * 4);
    float*  bufB    = (float*)take((size_t)N * 64 * 4);
    __half* Gh      = (__half*)take((size_t)N * 64 * 2);
    int*    rowptr  = (int*)take((size_t)N * 4);
    int*    rowend  = (int*)take((size_t)N * 4);
    float*  dinv    = (float*)take((size_t)N * 4);
    int*    bcur    = (int*)take((size_t)NBUCK * 4);

    const int* e_src = ei;
    const int* e_dst = ei + E;

    int chunk = (E + SCAT_BLOCKS - 1) / SCAT_BLOCKS;
    k_init<<<1, 1024, 0, stream>>>(bcur);
    k_scatter_fused<<<SCAT_BLOCKS, 256, 0, stream>>>(e_src, e_dst, bcur, staging, E, chunk);
    k_bucket_csr<<<NBUCK, 256, 0, stream>>>(staging, bcur, rowptr, rowend, ssoff, dinv, N);

    int tb = (N + 127) / 128;
    k_transform3<<<tb, 256, 0, stream>>>(x, W1, dinv, Gh, N);
    k_agg<<<(N + 3) / 4, 256, 0, stream>>>(Gh, rowptr, rowend, ssoff, dinv, b1, bufB, N);
    k_transform3<<<tb, 256, 0, stream>>>(bufB, W2, dinv, Gh, N);
    k_agg<<<(N + 3) / 4, 256, 0, stream>>>(Gh, rowptr, rowend, ssoff, dinv, b2, bufB, N);
    k_fc_softmax<<<(N * 16 + 255) / 256, 256, 0, stream>>>(bufB, Wfc, bfc, out, N);
}